// Round 9
// baseline (6241.297 us; speedup 1.0000x reference)
//
#include <hip/hip_runtime.h>

typedef unsigned int u32;
typedef unsigned short u16;
typedef __bf16 bf16x8 __attribute__((ext_vector_type(8)));
typedef u16 us8 __attribute__((ext_vector_type(8)));
typedef u32 u32x4 __attribute__((ext_vector_type(4)));
typedef float f32x4 __attribute__((ext_vector_type(4)));

#define T_N 256
#define B_N 64
#define NIN_N 256
#define H_N 2048
#define NOUT_N 256
#define BH (B_N * H_N)            // 131072
#define OUT_SZ (T_N * B_N * NOUT_N) // 4194304

// LDS: W_hi [4cs][16c][512] 64KB | Ah [16c][2rg][512] 32KB | Al 32KB | red 64B
#define LDS_W   0
#define LDS_AH  65536
#define LDS_AL  98304
#define LDS_RED 131072
#define LDS_BYTES 131136

struct U2 { u32 x, y; };

__device__ __forceinline__ u32 rotl32(u32 v, int r) { return (v << r) | (v >> (32 - r)); }

// JAX threefry-2x32, 20 rounds
__device__ __forceinline__ U2 tf2x32(U2 k, U2 x) {
  u32 ks0 = k.x, ks1 = k.y, ks2 = k.x ^ k.y ^ 0x1BD11BDAu;
  x.x += ks0; x.y += ks1;
#define TFR(a) x.x += x.y; x.y = rotl32(x.y,(a)); x.y ^= x.x;
  TFR(13) TFR(15) TFR(26) TFR(6)
  x.x += ks1; x.y += ks2 + 1u;
  TFR(17) TFR(29) TFR(16) TFR(24)
  x.x += ks2; x.y += ks0 + 2u;
  TFR(13) TFR(15) TFR(26) TFR(6)
  x.x += ks0; x.y += ks1 + 3u;
  TFR(17) TFR(29) TFR(16) TFR(24)
  x.x += ks1; x.y += ks2 + 4u;
  TFR(13) TFR(15) TFR(26) TFR(6)
  x.x += ks2; x.y += ks0 + 5u;
#undef TFR
  return x;
}

// JAX normal: uniform in [-1+2^-24, 1) -> sqrt(2)*erfinv (XLA f32 Giles polynomial)
__device__ __forceinline__ float jax_normal(u32 bits) {
  float f = __uint_as_float((bits >> 9) | 0x3f800000u) - 1.0f;
  const float lo = -0.99999994f;
  float u = fmaf(f, 2.0f, lo);
  u = fmaxf(u, lo);
  float w = -log1pf(-u * u);
  float p;
  if (w < 5.0f) {
    w = w - 2.5f;
    p =            2.81022636e-08f;
    p = fmaf(p, w, 3.43273939e-07f);
    p = fmaf(p, w, -3.5233877e-06f);
    p = fmaf(p, w, -4.39150654e-06f);
    p = fmaf(p, w, 0.00021858087f);
    p = fmaf(p, w, -0.00125372503f);
    p = fmaf(p, w, -0.00417768164f);
    p = fmaf(p, w, 0.246640727f);
    p = fmaf(p, w, 1.50140941f);
  } else {
    w = sqrtf(w) - 3.0f;
    p =            -0.000200214257f;
    p = fmaf(p, w, 0.000100950558f);
    p = fmaf(p, w, 0.00134934322f);
    p = fmaf(p, w, -0.00367342844f);
    p = fmaf(p, w, 0.00573950773f);
    p = fmaf(p, w, -0.0076224613f);
    p = fmaf(p, w, 0.00943887047f);
    p = fmaf(p, w, 1.00167406f);
    p = fmaf(p, w, 2.83297682f);
  }
  return 1.41421354f * (p * u);
}

__device__ __forceinline__ u16 f2bf(float f) {
  u32 x = __float_as_uint(f);
  u32 r = (x + 0x7FFFu + ((x >> 16) & 1u)) >> 16;
  return (u16)r;
}
__device__ __forceinline__ float bf2f(u16 b) { return __uint_as_float(((u32)b) << 16); }

__device__ __forceinline__ bf16x8 ld8(const u16* p) {
  us8 v = *reinterpret_cast<const us8*>(p);
  return __builtin_bit_cast(bf16x8, v);
}
__device__ __forceinline__ f32x4 mfma16(bf16x8 a, bf16x8 b, f32x4 c) {
  return __builtin_amdgcn_mfma_f32_16x16x32_bf16(a, b, c, 0, 0, 0);
}

// agent-scope (sc0 sc1) helpers: write-through to / read from die-level MALL
__device__ __forceinline__ void st_agent_u16(u16* p, u16 v) {
  __hip_atomic_store(p, v, __ATOMIC_RELAXED, __HIP_MEMORY_SCOPE_AGENT);
}
__device__ __forceinline__ void st_agent_u32(u32* p, u32 v, int order) {
  if (order) __hip_atomic_store(p, v, __ATOMIC_RELEASE, __HIP_MEMORY_SCOPE_AGENT);
  else       __hip_atomic_store(p, v, __ATOMIC_RELAXED, __HIP_MEMORY_SCOPE_AGENT);
}
__device__ __forceinline__ u32 ld_agent_u32(const u32* p) {
  return __hip_atomic_load(p, __ATOMIC_RELAXED, __HIP_MEMORY_SCOPE_AGENT);
}

// ---- Pack B-operand (W rows along n-dim): [R/16 tiles][K/32 chunks][64 lanes][8 bf16]
__global__ void __launch_bounds__(256) pack_b_kernel(const float* __restrict__ W,
    u16* __restrict__ hi, u16* __restrict__ lo, int K, int Cshift) {
  int tid = blockIdx.x * 256 + threadIdx.x;
  int lane = tid & 63;
  size_t tile = tid >> 6;
  int C = 1 << Cshift;
  int jt = (int)(tile >> Cshift), c = (int)(tile & (C - 1));
  int row = jt * 16 + (lane & 15);
  int k0 = c * 32 + (lane >> 4) * 8;
  const float* src = W + (size_t)row * K + k0;
  us8 vh, vl;
#pragma unroll
  for (int j = 0; j < 8; ++j) {
    float w = src[j];
    u16 hb = f2bf(w);
    vh[j] = hb;
    vl[j] = f2bf(w - bf2f(hb));
  }
  *reinterpret_cast<us8*>(hi + tile * 512 + lane * 8) = vh;
  *reinterpret_cast<us8*>(lo + tile * 512 + lane * 8) = vl;
}

// ---- Pack x (A-operand) per t
__global__ void __launch_bounds__(256) pack_x_kernel(const float* __restrict__ x,
    u16* __restrict__ hi, u16* __restrict__ lo) {
  int tid = blockIdx.x * 256 + threadIdx.x; // 524288
  int t = tid >> 11;
  int r = tid & 2047;
  int lane = r & 63, piece = r >> 6; // 0..31
  int c = piece >> 2, g = piece & 3;
  int row = g * 16 + (lane & 15);
  int k0 = c * 32 + (lane >> 4) * 8;
  const float* src = x + (size_t)t * (B_N * NIN_N) + (size_t)row * NIN_N + k0;
  us8 vh, vl;
#pragma unroll
  for (int j = 0; j < 8; ++j) {
    float w = src[j];
    u16 hb = f2bf(w);
    vh[j] = hb;
    vl[j] = f2bf(w - bf2f(hb));
  }
  size_t off = (size_t)t * 16384 + (size_t)piece * 512 + lane * 8;
  *reinterpret_cast<us8*>(hi + off) = vh;
  *reinterpret_cast<us8*>(lo + off) = vl;
}

// ---- Probe projections: xpj[p][col] = x[p][0][:] . W_ih[col][:] + b[col], f32
__global__ void __launch_bounds__(256) probe_proj(const float* __restrict__ x,
    const float* __restrict__ Wih, const float* __restrict__ bias, float* __restrict__ xpj) {
  int g = blockIdx.x * 256 + threadIdx.x;   // 4096
  int p = g >> 11, col = g & 2047;
  const float* xr = x + (size_t)p * (B_N * NIN_N);
  const float* wr = Wih + (size_t)col * NIN_N;
  float s = 0.f;
#pragma unroll 4
  for (int k = 0; k < NIN_N; ++k) s = fmaf(xr[k], wr[k], s);
  xpj[p * H_N + col] = s + bias[col];
}

// ---- xproj GEMM: hidden[t*BH + row*H + col] = x[t][row][:] . W_ih[col][:] + b[col]
__global__ void __launch_bounds__(256) xproj_gemm(const u16* __restrict__ xp_hi,
    const u16* __restrict__ xp_lo, const u16* __restrict__ wih_hi,
    const u16* __restrict__ wih_lo, const float* __restrict__ bias,
    float* __restrict__ xout) {
  int lane = threadIdx.x & 63, wvq = threadIdx.x >> 6;
  int t = blockIdx.x >> 7, jt16 = blockIdx.x & 127;
  const u16* ah = xp_hi + (size_t)t * 16384 + wvq * 512 + lane * 8;
  const u16* al = xp_lo + (size_t)t * 16384 + wvq * 512 + lane * 8;
  const u16* bh = wih_hi + (size_t)jt16 * 4096 + lane * 8;
  const u16* bl = wih_lo + (size_t)jt16 * 4096 + lane * 8;
  f32x4 z = {0.f, 0.f, 0.f, 0.f};
  f32x4 a0 = z, a1 = z, a2 = z;
#pragma unroll
  for (int c = 0; c < 8; ++c) {
    bf16x8 xh = ld8(ah + c * 2048), xl = ld8(al + c * 2048);
    bf16x8 wh = ld8(bh + c * 512),  wl = ld8(bl + c * 512);
    a0 = mfma16(xh, wh, a0);
    a1 = mfma16(xh, wl, a1);
    a2 = mfma16(xl, wh, a2);
  }
  f32x4 acc = (a0 + a1) + a2;
  int col = jt16 * 16 + (lane & 15);
  int q = lane >> 4;
  float bc = bias[col];
#pragma unroll
  for (int r = 0; r < 4; ++r) {
    int row = wvq * 16 + q * 4 + r;
    xout[(size_t)t * BH + (size_t)row * H_N + col] = acc[r] + bc;
  }
}

// ---- Keys (PARTITIONABLE threefry semantics)
__global__ void setup_keys(U2* ka, U2* kb, U2* ks) {
  int i = threadIdx.x;
  U2 base{0u, 42u};
  if (i < 104) {
    U2 ki = tf2x32(base, U2{0u, (u32)i});
    ka[i] = tf2x32(ki, U2{0u, 0u});
    kb[i] = tf2x32(ki, U2{0u, 1u});
  }
  U2 km = tf2x32(base, U2{0u, 1000000u});
  ks[i] = tf2x32(km, U2{0u, (u32)i});   // i in 0..255
}

__global__ void __launch_bounds__(256) zero_bufs(u32* hx0w, u32* hx0lw, u32* bar) {
  int g = blockIdx.x * 256 + threadIdx.x;   // 65536
  if (g < BH / 2) { hx0w[g] = 0u; hx0lw[g] = 0u; }
  if (g < 1024) bar[g] = 0u;
}

struct RnnParams {
  const u16 *whh_hi, *whh_lo;
  const float* xpj;          // [2][H] probe projections (+bias)
  float* hidden;             // = outbuf + OUT_SZ; pre-filled with xproj (+bias)
  u16 *hx0, *hx1, *hx2;      // init h (hi) buffers
  u16 *hx0l, *hx1l, *hx2l;   // init h (lo) buffers
  u16 *hS0, *hS1, *hS2;      // scan rotating h buffers
  float* pbuf;               // [3][256 blk][8 wv][64 lane] f32x4 partials
  const U2 *ka, *kb, *ks;
  u32 *slots, *mslot, *hflagI, *hflagS, *pflag;
};

// K-SPLIT persistent RNN. 256 blocks x 512 threads, 1 block/CU.
// block = (rh 0..1) x (ct 0..31: 64-col group) x (ks 0..3: K-quarter).
// wave wv = rg(2: 16-row) x cs(4: 16-col subtile). Each wave: one 16x16 MFMA
// tile over its K-quarter (no cross-wave reduce). A-slice (32 rows x 512 K,
// 32KB) staged ONCE into LDS per cell, shared by all 8 waves (4x less MALL
// traffic than per-16col-block reads). W_hi slice in LDS; W_lo from warm
// per-XCD L2 (read-only -> cache-safe). K-quarter partials exchanged as f32
// via MALL; ks==0 block reduces (same summation order as before), runs the
// epilogue (4 elems/thread), publishes h + per-group flag.
__global__ void __launch_bounds__(512) rnn_persistent(RnnParams P) {
  extern __shared__ char smem[];
  u16* lW  = (u16*)(smem + LDS_W);
  u16* lAh = (u16*)(smem + LDS_AH);
  u16* lAl = (u16*)(smem + LDS_AL);
  float* red = (float*)(smem + LDS_RED);
  u32* redu = (u32*)red;

  const int tid = threadIdx.x;
  const int lane = tid & 63;
  const int wv = tid >> 6;         // 0..7
  const int rg = wv >> 2;          // 0..1 row group
  const int cs = wv & 3;           // 0..3 col subtile
  const int blk = blockIdx.x;
  const int ks = blk & 3;          // K-quarter
  const int ct = (blk >> 2) & 31;  // 64-col group
  const int rh = blk >> 7;         // row half
  const int g = rh * 32 + ct;      // group id 0..63
  const int gb4 = blk & ~3;
  const bool isred = (ks == 0);
  const int hbase = rh * 32 + ks * 8;  // producer groups of my K-quarter

  // ---- stage W_hi slice into LDS: [cs][c][512]
  {
    const us8* src = (const us8*)P.whh_hi;
    us8* dst = (us8*)lW;
#pragma unroll
    for (int k = 0; k < 8; ++k) {
      int i = tid + 512 * k;
      int cs_ = i >> 10, ii = i & 1023, c_ = ii >> 6, l8 = ii & 63;
      dst[i] = src[(size_t)(ct * 4 + cs_) * 4096 + (size_t)(ks * 16 + c_) * 64 + l8];
    }
  }
  __syncthreads();
  // W_lo: global, L2-cached (read-only). chunk c at +c*512
  const u16* wlo = P.whh_lo + (size_t)(ct * 4 + cs) * 32768 + (size_t)ks * 8192 + lane * 8;

  // A staging offsets (u16 units); k-th load at +k*8192 src, +k*4096 dst
  const int c0 = tid >> 7, rgs = (tid >> 6) & 1, l8s = tid & 63;
  const u32 soff0 = (u32)(((ks * 16 + c0) * 4 + rh * 2 + rgs) * 64 + l8s) * 8;
  const u32 doff0 = (u32)((c0 * 2 + rgs) * 64 + l8s) * 8;

  auto stageA_hi = [&](const u16* hx) {
    const u16* p0 = hx + soff0;
    u32x4 V0, V1, V2, V3;
    asm volatile(
      "global_load_dwordx4 %0, %4, off sc0 sc1\n\t"
      "global_load_dwordx4 %1, %5, off sc0 sc1\n\t"
      "global_load_dwordx4 %2, %6, off sc0 sc1\n\t"
      "global_load_dwordx4 %3, %7, off sc0 sc1\n\t"
      "s_waitcnt vmcnt(0)"
      : "=&v"(V0), "=&v"(V1), "=&v"(V2), "=&v"(V3)
      : "v"(p0), "v"(p0 + 8192), "v"(p0 + 16384), "v"(p0 + 24576)
      : "memory");
    *(u32x4*)(lAh + doff0)         = V0;
    *(u32x4*)(lAh + doff0 + 4096)  = V1;
    *(u32x4*)(lAh + doff0 + 8192)  = V2;
    *(u32x4*)(lAh + doff0 + 12288) = V3;
  };
  auto stageA_hilo = [&](const u16* hxh, const u16* hxl) {
    const u16* p0 = hxh + soff0;
    const u16* q0 = hxl + soff0;
    u32x4 V0, V1, V2, V3, W0, W1, W2, W3;
    asm volatile(
      "global_load_dwordx4 %0, %8, off sc0 sc1\n\t"
      "global_load_dwordx4 %1, %9, off sc0 sc1\n\t"
      "global_load_dwordx4 %2, %10, off sc0 sc1\n\t"
      "global_load_dwordx4 %3, %11, off sc0 sc1\n\t"
      "global_load_dwordx4 %4, %12, off sc0 sc1\n\t"
      "global_load_dwordx4 %5, %13, off sc0 sc1\n\t"
      "global_load_dwordx4 %6, %14, off sc0 sc1\n\t"
      "global_load_dwordx4 %7, %15, off sc0 sc1\n\t"
      "s_waitcnt vmcnt(0)"
      : "=&v"(V0), "=&v"(V1), "=&v"(V2), "=&v"(V3),
        "=&v"(W0), "=&v"(W1), "=&v"(W2), "=&v"(W3)
      : "v"(p0), "v"(p0 + 8192), "v"(p0 + 16384), "v"(p0 + 24576),
        "v"(q0), "v"(q0 + 8192), "v"(q0 + 16384), "v"(q0 + 24576)
      : "memory");
    *(u32x4*)(lAh + doff0)         = V0;
    *(u32x4*)(lAh + doff0 + 4096)  = V1;
    *(u32x4*)(lAh + doff0 + 8192)  = V2;
    *(u32x4*)(lAh + doff0 + 12288) = V3;
    *(u32x4*)(lAl + doff0)         = W0;
    *(u32x4*)(lAl + doff0 + 4096)  = W1;
    *(u32x4*)(lAl + doff0 + 8192)  = W2;
    *(u32x4*)(lAl + doff0 + 12288) = W3;
  };

  // wave0 polls the 8 producer-group flags of this block's K-quarter
  auto pollH = [&](const u32* flags, u32 need) {
    if (wv == 0) {
      const u32* p = flags + hbase + (lane & 7);
      for (;;) {
        u32 v;
        asm volatile("global_load_dword %0, %1, off sc0 sc1\n\ts_waitcnt vmcnt(0)"
                     : "=v"(v) : "v"(p) : "memory");
        if (__all(v >= need)) break;
        __builtin_amdgcn_s_sleep(2);
      }
    }
    __syncthreads();
  };

  // ks!=0: store partial + release pflag; all: ack + block sync
  auto store_partial = [&](f32x4 p, u32 pe) {
    if (!isred) {
      float* addr = P.pbuf + ((size_t)(pe % 3) * 256 + blk) * 2048 + (size_t)(wv * 64 + lane) * 4;
      asm volatile("global_store_dwordx4 %0, %1, off sc0 sc1" :: "v"(addr), "v"(p) : "memory");
    }
    asm volatile("s_waitcnt vmcnt(0)" ::: "memory");
    __syncthreads();
    if (!isred && tid == 0) st_agent_u32(P.pflag + blk, pe, 1);
  };

  // ks==0: poll partners' pflags, read 3 partials, sum in fixed order
  auto gather_sum = [&](f32x4 own, u32 pe) -> f32x4 {
    const u32* fp = P.pflag + gb4;
    for (;;) {
      u32x4 pr;
      asm volatile("global_load_dwordx4 %0, %1, off sc0 sc1\n\ts_waitcnt vmcnt(0)"
                   : "=&v"(pr) : "v"(fp) : "memory");
      if (pr.y >= pe && pr.z >= pe && pr.w >= pe) break;
      __builtin_amdgcn_s_sleep(1);
    }
    const float* pb = P.pbuf + (size_t)(pe % 3) * 256 * 2048 + (size_t)(wv * 64 + lane) * 4;
    f32x4 q1, q2, q3;
    asm volatile(
      "global_load_dwordx4 %0, %3, off sc0 sc1\n\t"
      "global_load_dwordx4 %1, %4, off sc0 sc1\n\t"
      "global_load_dwordx4 %2, %5, off sc0 sc1\n\t"
      "s_waitcnt vmcnt(0)"
      : "=&v"(q1), "=&v"(q2), "=&v"(q3)
      : "v"(pb + (size_t)(gb4 + 1) * 2048), "v"(pb + (size_t)(gb4 + 2) * 2048),
        "v"(pb + (size_t)(gb4 + 3) * 2048)
      : "memory");
    return ((own + q1) + q2) + q3;   // ks0 + ks1 + ks2 + ks3, as before
  };

  // GEMMs: same per-chunk accumulator grouping as prior rounds (bit-identical)
  auto gemm_hi = [&]() -> f32x4 {
    f32x4 z = {0.f, 0.f, 0.f, 0.f};
    f32x4 a0 = z, a1 = z, a2 = z, a3 = z;
    const u16* Ab = lAh + rg * 512 + lane * 8;
    const u16* Wb = lW + cs * 8192 + lane * 8;
#pragma unroll
    for (int c = 0; c < 16; ++c) {
      bf16x8 av = ld8(Ab + c * 1024);
      bf16x8 bh = ld8(Wb + c * 512);
      bf16x8 bl = ld8(wlo + c * 512);
      if (c & 1) { a2 = mfma16(av, bh, a2); a3 = mfma16(av, bl, a3); }
      else       { a0 = mfma16(av, bh, a0); a1 = mfma16(av, bl, a1); }
    }
    return (a0 + a1) + (a2 + a3);
  };
  auto gemm_hilo = [&]() -> f32x4 {
    f32x4 z = {0.f, 0.f, 0.f, 0.f};
    f32x4 a0 = z, a1 = z, a2 = z, a3 = z, a4 = z, a5 = z;
    const u16* Abh = lAh + rg * 512 + lane * 8;
    const u16* Abl = lAl + rg * 512 + lane * 8;
    const u16* Wb = lW + cs * 8192 + lane * 8;
#pragma unroll
    for (int c = 0; c < 16; ++c) {
      bf16x8 ah = ld8(Abh + c * 1024);
      bf16x8 al = ld8(Abl + c * 1024);
      bf16x8 bh = ld8(Wb + c * 512);
      bf16x8 bl = ld8(wlo + c * 512);
      if (c & 1) { a3 = mfma16(ah, bh, a3); a4 = mfma16(ah, bl, a4); a5 = mfma16(al, bh, a5); }
      else       { a0 = mfma16(ah, bh, a0); a1 = mfma16(ah, bl, a1); a2 = mfma16(al, bh, a2); }
    }
    return ((a0 + a1) + (a2 + a3)) + (a4 + a5);
  };

  // element ownership (ks0 blocks): 4 elems per thread, rows row0+j, col col0
  const int row0 = rh * 32 + rg * 16 + (lane >> 4) * 4;
  const int col0 = ct * 64 + cs * 16 + (lane & 15);
  const u32 idx0 = (u32)row0 * H_N + (u32)col0;
  const u32 xoff0 = ((u32)((col0 >> 5) * 4 + (row0 >> 4)) * 64
                    + (u32)(((col0 >> 3) & 3) * 16 + (row0 & 15))) * 8 + (u32)(col0 & 7);

  auto noise4 = [&](U2 key) -> f32x4 {
    f32x4 r;
#pragma unroll
    for (int j = 0; j < 4; ++j) {
      U2 o = tf2x32(key, U2{0u, idx0 + (u32)j * 2048u});
      r[j] = jax_normal(o.x ^ o.y);
    }
    return r;
  };

  u32 ebar = 0;
  auto bar_agg = [&]() {
    ++ebar;
    asm volatile("s_waitcnt vmcnt(0)" ::: "memory");
    __syncthreads();
    if (tid == 0) {
      if (isred) {
        float m = red[0];
#pragma unroll
        for (int w2 = 1; w2 < 8; ++w2) m = fmaxf(m, red[w2]);
        st_agent_u32(P.mslot + g, __float_as_uint(m), 0);
      }
      st_agent_u32(P.slots + blk, ebar, 1);
    }
    if (wv == 0) {
      const u32* ps = P.slots + lane * 4;
      for (;;) {
        u32x4 pr;
        asm volatile("global_load_dwordx4 %0, %1, off sc0 sc1\n\ts_waitcnt vmcnt(0)"
                     : "=&v"(pr) : "v"(ps) : "memory");
        u32 mn = pr.x < pr.y ? pr.x : pr.y;
        u32 mn2 = pr.z < pr.w ? pr.z : pr.w;
        mn = mn < mn2 ? mn : mn2;
        if (__all(mn >= ebar)) break;
        __builtin_amdgcn_s_sleep(1);
      }
      float m = __uint_as_float(ld_agent_u32(P.mslot + lane));
#pragma unroll
      for (int o = 32; o >= 1; o >>= 1) m = fmaxf(m, __shfl_down(m, o));
      if (lane == 0) redu[8] = (m <= 0.1f) ? 1u : 0u;
    }
    __syncthreads();
  };

  const float NS = 0.15811388300841897f;
  const float xv0 = P.xpj[col0];          // probe x same across batch rows
  const float xv1 = P.xpj[H_N + col0];

  u16* hxs[3]  = {P.hx0, P.hx1, P.hx2};
  u16* hxls[3] = {P.hx0l, P.hx1l, P.hx2l};
  int i0 = 0, i1 = 1, i2 = 2;
  f32x4 zero4 = {0.f, 0.f, 0.f, 0.f};
  f32x4 hp0 = zero4, hp2 = zero4;
  int stable = 0;
  u32 pep = 0;
  f32x4 nzA = isred ? noise4(P.ka[0]) : zero4;

  // ---- init loop (fp32-faithful via hi+lo activations)
#pragma unroll 1
  for (int it = 0; it < 100; ++it) {
    // cell1 (reads i0; ordered by previous bar_agg / zero_bufs)
    ++pep;
    stageA_hilo(hxs[i0], hxls[i0]);
    __syncthreads();
    f32x4 nzB = isred ? noise4(P.kb[it]) : zero4;
    f32x4 p = gemm_hilo();
    store_partial(p, pep);
    f32x4 hp1 = zero4;
    if (isred) {
      f32x4 av = gather_sum(p, pep);
#pragma unroll
      for (int j = 0; j < 4; ++j) {
        float pre = av[j] + xv0 + NS * nzA[j];
        hp1[j] = 0.8f * hp0[j] + 0.2f * fmaxf(pre, 0.f);
        u16 hb = f2bf(hp1[j]);
        st_agent_u16(hxs[i1] + xoff0 + j * 8, hb);
        st_agent_u16(hxls[i1] + xoff0 + j * 8, f2bf(hp1[j] - bf2f(hb)));
      }
      asm volatile("s_waitcnt vmcnt(0)" ::: "memory");
      __syncthreads();
      if (tid == 0) st_agent_u32(P.hflagI + g, (u32)(it + 1), 1);
    }
    // cell2 (reads i1; gated on hflagI)
    ++pep;
    pollH(P.hflagI, (u32)(it + 1));
    stageA_hilo(hxs[i1], hxls[i1]);
    __syncthreads();
    if (isred) nzA = noise4(P.ka[it + 1]);
    p = gemm_hilo();
    store_partial(p, pep);
    if (isred) {
      f32x4 av = gather_sum(p, pep);
      float lmax = 0.f;
#pragma unroll
      for (int j = 0; j < 4; ++j) {
        float pre = av[j] + xv1 + NS * nzB[j];
        hp2[j] = 0.8f * hp1[j] + 0.2f * fmaxf(pre, 0.f);
        u16 hb = f2bf(hp2[j]);
        st_agent_u16(hxs[i2] + xoff0 + j * 8, hb);
        st_agent_u16(hxls[i2] + xoff0 + j * 8, f2bf(hp2[j] - bf2f(hb)));
        lmax = fmaxf(lmax, fabsf(hp2[j] - hp0[j]));
      }
#pragma unroll
      for (int o = 32; o >= 1; o >>= 1) lmax = fmaxf(lmax, __shfl_down(lmax, o));
      if (lane == 0) red[wv] = lmax;
    }
    bar_agg();
    bool close = (redu[8] & 1u) != 0u;
    if (close) {
      if (++stable >= 4) break;   // h0 = hxs[i0] input of this iteration
    } else stable = 0;
    int tmp = i0; i0 = i2; i2 = tmp;
    hp0 = hp2;
  }

  // ---- main scan: K-split dataflow, 3 rotating h buffers
  u16* bufS[3] = {P.hS0, P.hS1, P.hS2};
  f32x4 hp = hp0;
  f32x4 nzS = isred ? noise4(P.ks[0]) : zero4;
  f32x4 xvS = zero4;
  if (isred) {
#pragma unroll
    for (int j = 0; j < 4; ++j) xvS[j] = P.hidden[idx0 + (u32)j * 2048];
  }
#pragma unroll 1
  for (int t = 0; t < T_N; ++t) {
    ++pep;
    if (t) pollH(P.hflagS, (u32)(t + 1));
    stageA_hi(t == 0 ? hxs[i0] : bufS[t % 3]);
    __syncthreads();
    f32x4 p = gemm_hi();
    store_partial(p, pep);
    if (isred) {
      f32x4 av = gather_sum(p, pep);
      f32x4 hn;
#pragma unroll
      for (int j = 0; j < 4; ++j) {
        float pre = av[j] + xvS[j] + NS * nzS[j];
        hn[j] = 0.8f * hp[j] + 0.2f * fmaxf(pre, 0.f);
      }
      hp = hn;
#pragma unroll
      for (int j = 0; j < 4; ++j)
        P.hidden[(size_t)t * BH + idx0 + (u32)j * 2048] = hn[j];
      if (t != T_N - 1) {
        u16* hb = bufS[(t + 1) % 3];
#pragma unroll
        for (int j = 0; j < 4; ++j) st_agent_u16(hb + xoff0 + j * 8, f2bf(hn[j]));
        asm volatile("s_waitcnt vmcnt(0)" ::: "memory");
        __syncthreads();
        if (tid == 0) st_agent_u32(P.hflagS + g, (u32)(t + 2), 1);
        nzS = noise4(P.ks[t + 1]);
#pragma unroll
        for (int j = 0; j < 4; ++j)
          xvS[j] = P.hidden[(size_t)(t + 1) * BH + idx0 + (u32)j * 2048];
      }
    }
  }
}

// ---- output GEMM: out[M=16384][256] = hidden(bf16) @ Wout^T (hi+lo)
__global__ void __launch_bounds__(256) out_gemm(const float* __restrict__ hidden,
    const u16* __restrict__ wo_hi, const u16* __restrict__ wo_lo, float* __restrict__ out) {
  int lane = threadIdx.x & 63, wv = threadIdx.x >> 6;
  int mb = blockIdx.x * 64 + wv * 16;
  int arow = mb + (lane & 15);
  int q = lane >> 4;
  f32x4 acc[16];
#pragma unroll
  for (int n = 0; n < 16; ++n) acc[n] = {0.f, 0.f, 0.f, 0.f};
  const float* ap = hidden + (size_t)arow * H_N + q * 8;
#pragma unroll 2
  for (int c = 0; c < 64; ++c) {
    const float4* a4 = reinterpret_cast<const float4*>(ap + c * 32);
    float4 f0 = a4[0], f1 = a4[1];
    us8 av;
    av[0] = f2bf(f0.x); av[1] = f2bf(f0.y); av[2] = f2bf(f0.z); av[3] = f2bf(f0.w);
    av[4] = f2bf(f1.x); av[5] = f2bf(f1.y); av[6] = f2bf(f1.z); av[7] = f2bf(f1.w);
    bf16x8 a = __builtin_bit_cast(bf16x8, av);
#pragma unroll
    for (int n = 0; n < 16; ++n) {
      bf16x8 bh = ld8(wo_hi + ((size_t)(n * 64 + c) * 64 + lane) * 8);
      bf16x8 bl = ld8(wo_lo + ((size_t)(n * 64 + c) * 64 + lane) * 8);
      acc[n] = mfma16(a, bh, acc[n]);
      acc[n] = mfma16(a, bl, acc[n]);
    }
  }
#pragma unroll
  for (int n = 0; n < 16; ++n)
#pragma unroll
    for (int r = 0; r < 4; ++r)
      out[(size_t)(mb + q * 4 + r) * NOUT_N + n * 16 + (lane & 15)] = acc[n][r];
}

extern "C" void kernel_launch(void* const* d_in, const int* in_sizes, int n_in,
                              void* d_out, int out_size, void* d_ws, size_t ws_size,
                              hipStream_t stream) {
  const float* x = (const float*)d_in[0];
  const float* W_ih = (const float*)d_in[1];
  const float* W_hh = (const float*)d_in[2];
  const float* bias = (const float*)d_in[3];
  const float* W_out = (const float*)d_in[4];
  float* out = (float*)d_out;

  char* ws = (char*)d_ws;
  size_t off = 0;
  auto alloc = [&](size_t bytes) -> void* {
    void* p = ws + off;
    off += (bytes + 255) & ~(size_t)255;
    return p;
  };
  u16* whh_hi = (u16*)alloc(8388608);
  u16* whh_lo = (u16*)alloc(8388608);
  u16* wih_hi = (u16*)alloc(1048576);
  u16* wih_lo = (u16*)alloc(1048576);
  u16* wout_hi = (u16*)alloc(1048576);
  u16* wout_lo = (u16*)alloc(1048576);
  u16* xp_hi = (u16*)alloc(8388608);
  u16* xp_lo = (u16*)alloc(8388608);
  float* xpj = (float*)alloc(16384);
  u16* hx0 = (u16*)alloc(262144);
  u16* hx1 = (u16*)alloc(262144);
  u16* hx2 = (u16*)alloc(262144);
  u16* hx0l = (u16*)alloc(262144);
  u16* hx1l = (u16*)alloc(262144);
  u16* hx2l = (u16*)alloc(262144);
  u16* hS0 = (u16*)alloc(262144);
  u16* hS1 = (u16*)alloc(262144);
  u16* hS2 = (u16*)alloc(262144);
  float* pbuf = (float*)alloc(6291456);
  U2* ka = (U2*)alloc(832);
  U2* kb = (U2*)alloc(832);
  U2* ks = (U2*)alloc(2048);
  u32* bar = (u32*)alloc(4096);

  float* hidden = out + OUT_SZ;

  hipLaunchKernelGGL(pack_b_kernel, dim3(2048), dim3(256), 0, stream, W_hh, whh_hi, whh_lo, 2048, 6);
  hipLaunchKernelGGL(pack_b_kernel, dim3(256), dim3(256), 0, stream, W_ih, wih_hi, wih_lo, 256, 3);
  hipLaunchKernelGGL(pack_b_kernel, dim3(256), dim3(256), 0, stream, W_out, wout_hi, wout_lo, 2048, 6);
  hipLaunchKernelGGL(pack_x_kernel, dim3(2048), dim3(256), 0, stream, x, xp_hi, xp_lo);
  hipLaunchKernelGGL(probe_proj, dim3(16), dim3(256), 0, stream, x, W_ih, bias, xpj);
  hipLaunchKernelGGL(setup_keys, dim3(1), dim3(256), 0, stream, ka, kb, ks);
  hipLaunchKernelGGL(zero_bufs, dim3(256), dim3(256), 0, stream, (u32*)hx0, (u32*)hx0l, bar);
  hipLaunchKernelGGL(xproj_gemm, dim3(32768), dim3(256), 0, stream, xp_hi, xp_lo, wih_hi, wih_lo, bias, hidden);

  RnnParams P;
  P.whh_hi = whh_hi; P.whh_lo = whh_lo;
  P.xpj = xpj;
  P.hidden = hidden;
  P.hx0 = hx0; P.hx1 = hx1; P.hx2 = hx2;
  P.hx0l = hx0l; P.hx1l = hx1l; P.hx2l = hx2l;
  P.hS0 = hS0; P.hS1 = hS1; P.hS2 = hS2;
  P.pbuf = pbuf;
  P.ka = ka; P.kb = kb; P.ks = ks;
  P.slots = bar; P.mslot = bar + 256; P.hflagI = bar + 320;
  P.hflagS = bar + 384; P.pflag = bar + 448;

  static bool attr_set = false;
  if (!attr_set) {
    hipFuncSetAttribute((const void*)rnn_persistent,
                        hipFuncAttributeMaxDynamicSharedMemorySize, LDS_BYTES);
    attr_set = true;
  }

  void* kargs[] = {(void*)&P};
  hipLaunchCooperativeKernel((const void*)rnn_persistent, dim3(256), dim3(512), kargs, LDS_BYTES, stream);

  hipLaunchKernelGGL(out_gemm, dim3(256), dim3(256), 0, stream, hidden, wout_hi, wout_lo, out);
}

// Round 10
// 5121.789 us; speedup vs baseline: 1.2186x; 1.2186x over previous
//
#include <hip/hip_runtime.h>

typedef unsigned int u32;
typedef unsigned short u16;
typedef __bf16 bf16x8 __attribute__((ext_vector_type(8)));
typedef u16 us8 __attribute__((ext_vector_type(8)));
typedef u32 u32x4 __attribute__((ext_vector_type(4)));
typedef float f32x4 __attribute__((ext_vector_type(4)));

#define T_N 256
#define B_N 64
#define NIN_N 256
#define H_N 2048
#define NOUT_N 256
#define BH (B_N * H_N)            // 131072
#define OUT_SZ (T_N * B_N * NOUT_N) // 4194304

// LDS: whh_hi 64KB | whh_lo 64KB | rbuf 8KB | red 64B
#define LDS_WHH_H 0
#define LDS_WHH_L 65536
#define LDS_RBUF  131072
#define LDS_RED   139264
#define LDS_BYTES 139328

struct U2 { u32 x, y; };

__device__ __forceinline__ u32 rotl32(u32 v, int r) { return (v << r) | (v >> (32 - r)); }

// JAX threefry-2x32, 20 rounds
__device__ __forceinline__ U2 tf2x32(U2 k, U2 x) {
  u32 ks0 = k.x, ks1 = k.y, ks2 = k.x ^ k.y ^ 0x1BD11BDAu;
  x.x += ks0; x.y += ks1;
#define TFR(a) x.x += x.y; x.y = rotl32(x.y,(a)); x.y ^= x.x;
  TFR(13) TFR(15) TFR(26) TFR(6)
  x.x += ks1; x.y += ks2 + 1u;
  TFR(17) TFR(29) TFR(16) TFR(24)
  x.x += ks2; x.y += ks0 + 2u;
  TFR(13) TFR(15) TFR(26) TFR(6)
  x.x += ks0; x.y += ks1 + 3u;
  TFR(17) TFR(29) TFR(16) TFR(24)
  x.x += ks1; x.y += ks2 + 4u;
  TFR(13) TFR(15) TFR(26) TFR(6)
  x.x += ks2; x.y += ks0 + 5u;
#undef TFR
  return x;
}

// JAX normal: uniform in [-1+2^-24, 1) -> sqrt(2)*erfinv (XLA f32 Giles polynomial)
__device__ __forceinline__ float jax_normal(u32 bits) {
  float f = __uint_as_float((bits >> 9) | 0x3f800000u) - 1.0f;
  const float lo = -0.99999994f;
  float u = fmaf(f, 2.0f, lo);
  u = fmaxf(u, lo);
  float w = -log1pf(-u * u);
  float p;
  if (w < 5.0f) {
    w = w - 2.5f;
    p =            2.81022636e-08f;
    p = fmaf(p, w, 3.43273939e-07f);
    p = fmaf(p, w, -3.5233877e-06f);
    p = fmaf(p, w, -4.39150654e-06f);
    p = fmaf(p, w, 0.00021858087f);
    p = fmaf(p, w, -0.00125372503f);
    p = fmaf(p, w, -0.00417768164f);
    p = fmaf(p, w, 0.246640727f);
    p = fmaf(p, w, 1.50140941f);
  } else {
    w = sqrtf(w) - 3.0f;
    p =            -0.000200214257f;
    p = fmaf(p, w, 0.000100950558f);
    p = fmaf(p, w, 0.00134934322f);
    p = fmaf(p, w, -0.00367342844f);
    p = fmaf(p, w, 0.00573950773f);
    p = fmaf(p, w, -0.0076224613f);
    p = fmaf(p, w, 0.00943887047f);
    p = fmaf(p, w, 1.00167406f);
    p = fmaf(p, w, 2.83297682f);
  }
  return 1.41421354f * (p * u);
}

__device__ __forceinline__ u16 f2bf(float f) {
  u32 x = __float_as_uint(f);
  u32 r = (x + 0x7FFFu + ((x >> 16) & 1u)) >> 16;
  return (u16)r;
}
__device__ __forceinline__ float bf2f(u16 b) { return __uint_as_float(((u32)b) << 16); }

__device__ __forceinline__ bf16x8 ld8(const u16* p) {
  us8 v = *reinterpret_cast<const us8*>(p);
  return __builtin_bit_cast(bf16x8, v);
}
__device__ __forceinline__ f32x4 mfma16(bf16x8 a, bf16x8 b, f32x4 c) {
  return __builtin_amdgcn_mfma_f32_16x16x32_bf16(a, b, c, 0, 0, 0);
}

// agent-scope (sc0 sc1) helpers: write-through to / read from die-level MALL
__device__ __forceinline__ void st_agent_u16(u16* p, u16 v) {
  __hip_atomic_store(p, v, __ATOMIC_RELAXED, __HIP_MEMORY_SCOPE_AGENT);
}
__device__ __forceinline__ void st_agent_u32(u32* p, u32 v, int order) {
  if (order) __hip_atomic_store(p, v, __ATOMIC_RELEASE, __HIP_MEMORY_SCOPE_AGENT);
  else       __hip_atomic_store(p, v, __ATOMIC_RELAXED, __HIP_MEMORY_SCOPE_AGENT);
}
__device__ __forceinline__ u32 ld_agent_u32(const u32* p) {
  return __hip_atomic_load(p, __ATOMIC_RELAXED, __HIP_MEMORY_SCOPE_AGENT);
}

// 16 coherent (L1+L2-bypass) 16B loads: chunks c=0..15 at AP + c*2048 u16.
#define GLD16(AP, V) \
  asm volatile( \
    "global_load_dwordx4 %0, %16, off offset:-4096 sc0 sc1\n\t" \
    "global_load_dwordx4 %1, %16, off sc0 sc1\n\t" \
    "global_load_dwordx4 %2, %17, off offset:-4096 sc0 sc1\n\t" \
    "global_load_dwordx4 %3, %17, off sc0 sc1\n\t" \
    "global_load_dwordx4 %4, %18, off offset:-4096 sc0 sc1\n\t" \
    "global_load_dwordx4 %5, %18, off sc0 sc1\n\t" \
    "global_load_dwordx4 %6, %19, off offset:-4096 sc0 sc1\n\t" \
    "global_load_dwordx4 %7, %19, off sc0 sc1\n\t" \
    "global_load_dwordx4 %8, %20, off offset:-4096 sc0 sc1\n\t" \
    "global_load_dwordx4 %9, %20, off sc0 sc1\n\t" \
    "global_load_dwordx4 %10, %21, off offset:-4096 sc0 sc1\n\t" \
    "global_load_dwordx4 %11, %21, off sc0 sc1\n\t" \
    "global_load_dwordx4 %12, %22, off offset:-4096 sc0 sc1\n\t" \
    "global_load_dwordx4 %13, %22, off sc0 sc1\n\t" \
    "global_load_dwordx4 %14, %23, off offset:-4096 sc0 sc1\n\t" \
    "global_load_dwordx4 %15, %23, off sc0 sc1\n\t" \
    "s_waitcnt vmcnt(0)" \
    : "=&v"(V##0), "=&v"(V##1), "=&v"(V##2), "=&v"(V##3), \
      "=&v"(V##4), "=&v"(V##5), "=&v"(V##6), "=&v"(V##7), \
      "=&v"(V##8), "=&v"(V##9), "=&v"(V##10), "=&v"(V##11), \
      "=&v"(V##12), "=&v"(V##13), "=&v"(V##14), "=&v"(V##15) \
    : "v"(AP + 2048), "v"(AP + 3 * 2048), "v"(AP + 5 * 2048), "v"(AP + 7 * 2048), \
      "v"(AP + 9 * 2048), "v"(AP + 11 * 2048), "v"(AP + 13 * 2048), "v"(AP + 15 * 2048) \
    : "memory")

// ---- Pack B-operand (W rows along n-dim): [R/16 tiles][K/32 chunks][64 lanes][8 bf16]
__global__ void __launch_bounds__(256) pack_b_kernel(const float* __restrict__ W,
    u16* __restrict__ hi, u16* __restrict__ lo, int K, int Cshift) {
  int tid = blockIdx.x * 256 + threadIdx.x;
  int lane = tid & 63;
  size_t tile = tid >> 6;
  int C = 1 << Cshift;
  int jt = (int)(tile >> Cshift), c = (int)(tile & (C - 1));
  int row = jt * 16 + (lane & 15);
  int k0 = c * 32 + (lane >> 4) * 8;
  const float* src = W + (size_t)row * K + k0;
  us8 vh, vl;
#pragma unroll
  for (int j = 0; j < 8; ++j) {
    float w = src[j];
    u16 hb = f2bf(w);
    vh[j] = hb;
    vl[j] = f2bf(w - bf2f(hb));
  }
  *reinterpret_cast<us8*>(hi + tile * 512 + lane * 8) = vh;
  *reinterpret_cast<us8*>(lo + tile * 512 + lane * 8) = vl;
}

// ---- Pack x (A-operand) per t
__global__ void __launch_bounds__(256) pack_x_kernel(const float* __restrict__ x,
    u16* __restrict__ hi, u16* __restrict__ lo) {
  int tid = blockIdx.x * 256 + threadIdx.x; // 524288
  int t = tid >> 11;
  int r = tid & 2047;
  int lane = r & 63, piece = r >> 6; // 0..31
  int c = piece >> 2, g = piece & 3;
  int row = g * 16 + (lane & 15);
  int k0 = c * 32 + (lane >> 4) * 8;
  const float* src = x + (size_t)t * (B_N * NIN_N) + (size_t)row * NIN_N + k0;
  us8 vh, vl;
#pragma unroll
  for (int j = 0; j < 8; ++j) {
    float w = src[j];
    u16 hb = f2bf(w);
    vh[j] = hb;
    vl[j] = f2bf(w - bf2f(hb));
  }
  size_t off = (size_t)t * 16384 + (size_t)piece * 512 + lane * 8;
  *reinterpret_cast<us8*>(hi + off) = vh;
  *reinterpret_cast<us8*>(lo + off) = vl;
}

// ---- Probe projections: xpj[p][col] = x[p][0][:] . W_ih[col][:] + b[col], f32
__global__ void __launch_bounds__(256) probe_proj(const float* __restrict__ x,
    const float* __restrict__ Wih, const float* __restrict__ bias, float* __restrict__ xpj) {
  int g = blockIdx.x * 256 + threadIdx.x;   // 4096
  int p = g >> 11, col = g & 2047;
  const float* xr = x + (size_t)p * (B_N * NIN_N);
  const float* wr = Wih + (size_t)col * NIN_N;
  float s = 0.f;
#pragma unroll 4
  for (int k = 0; k < NIN_N; ++k) s = fmaf(xr[k], wr[k], s);
  xpj[p * H_N + col] = s + bias[col];
}

// ---- xproj GEMM: hidden[t*BH + row*H + col] = x[t][row][:] . W_ih[col][:] + b[col]
__global__ void __launch_bounds__(256) xproj_gemm(const u16* __restrict__ xp_hi,
    const u16* __restrict__ xp_lo, const u16* __restrict__ wih_hi,
    const u16* __restrict__ wih_lo, const float* __restrict__ bias,
    float* __restrict__ xout) {
  int lane = threadIdx.x & 63, wvq = threadIdx.x >> 6;
  int t = blockIdx.x >> 7, jt16 = blockIdx.x & 127;
  const u16* ah = xp_hi + (size_t)t * 16384 + wvq * 512 + lane * 8;
  const u16* al = xp_lo + (size_t)t * 16384 + wvq * 512 + lane * 8;
  const u16* bh = wih_hi + (size_t)jt16 * 4096 + lane * 8;
  const u16* bl = wih_lo + (size_t)jt16 * 4096 + lane * 8;
  f32x4 z = {0.f, 0.f, 0.f, 0.f};
  f32x4 a0 = z, a1 = z, a2 = z;
#pragma unroll
  for (int c = 0; c < 8; ++c) {
    bf16x8 xh = ld8(ah + c * 2048), xl = ld8(al + c * 2048);
    bf16x8 wh = ld8(bh + c * 512),  wl = ld8(bl + c * 512);
    a0 = mfma16(xh, wh, a0);
    a1 = mfma16(xh, wl, a1);
    a2 = mfma16(xl, wh, a2);
  }
  f32x4 acc = (a0 + a1) + a2;
  int col = jt16 * 16 + (lane & 15);
  int q = lane >> 4;
  float bc = bias[col];
#pragma unroll
  for (int r = 0; r < 4; ++r) {
    int row = wvq * 16 + q * 4 + r;
    xout[(size_t)t * BH + (size_t)row * H_N + col] = acc[r] + bc;
  }
}

// ---- Keys (PARTITIONABLE threefry semantics)
__global__ void setup_keys(U2* ka, U2* kb, U2* ks) {
  int i = threadIdx.x;
  U2 base{0u, 42u};
  if (i < 104) {
    U2 ki = tf2x32(base, U2{0u, (u32)i});
    ka[i] = tf2x32(ki, U2{0u, 0u});
    kb[i] = tf2x32(ki, U2{0u, 1u});
  }
  U2 km = tf2x32(base, U2{0u, 1000000u});
  ks[i] = tf2x32(km, U2{0u, (u32)i});   // i in 0..255
}

__global__ void __launch_bounds__(256) zero_bufs(u32* hx0w, u32* hx0lw, u32* bar) {
  int g = blockIdx.x * 256 + threadIdx.x;   // 65536
  if (g < BH / 2) { hx0w[g] = 0u; hx0lw[g] = 0u; }
  if (g < 1024) bar[g] = 0u;
}

struct RnnParams {
  const u16 *whh_hi, *whh_lo;
  const float* xpj;          // [2][H] probe projections (+bias)
  float* hidden;             // = outbuf + OUT_SZ; pre-filled with xproj (+bias)
  u16 *hx0, *hx1, *hx2;      // init h (hi) buffers
  u16 *hx0l, *hx1l, *hx2l;   // init h (lo) buffers
  u16 *hxS0, *hxS1, *hxS2;   // scan rotating h buffers (3-deep)
  const U2 *ka, *kb, *ks;
  u32 *slots, *mslot;        // agg barrier: [256] epochs, [256] max bits
  u32 *initflag, *scanflag;  // [256] monotonic producer flags
};

// 256 blocks x 512 threads, 1 block/CU. block = (rh 0..1) x (jt16 0..127).
// wave = rg(2) x kh(4). Each thread owns ONE (row,col) h element forever.
// W_hh slice in LDS. h exchange: write-through agent stores + sc0sc1 bypass
// loads from MALL. Sync: producer-gated dataflow with SINGLE-POLLER blocks —
// wave0 polls the 128 same-rh producer flags (one dwordx4 instruction), the
// other 7 waves sleep at __syncthreads (kills the 2048-wave flag-poll storm).
__global__ void __launch_bounds__(512) rnn_persistent(RnnParams P) {
  extern __shared__ char smem[];
  u16* lwhh_h = (u16*)(smem + LDS_WHH_H);
  u16* lwhh_l = (u16*)(smem + LDS_WHH_L);
  f32x4* rbuf = (f32x4*)(smem + LDS_RBUF);   // [8 waves][64 lanes]
  float* red  = (float*)(smem + LDS_RED);    // [0..7] wave maxes, [8] flag word

  const int lane = threadIdx.x & 63;
  const int wv = threadIdx.x >> 6;   // 0..7
  const int rg = wv >> 2;            // 0..1
  const int kh = wv & 3;             // 0..3 K-quarter
  const int blk = blockIdx.x;        // 0..255
  const int jt16 = blk & 127;
  const int rh = blk >> 7;
  const int bqg = rh * 2 + rg;       // 16-row group 0..3
  const int q = lane >> 4;
  const int row = bqg * 16 + q * 4 + kh;        // batch row owned by this thread
  const int col = jt16 * 16 + (lane & 15);      // H col owned by this thread
  const u32 idx = (u32)row * H_N + (u32)col;
  const u32 xoff = ((u32)((col >> 5) * 4 + (row >> 4)) * 64
                    + (u32)(((col >> 3) & 3) * 16 + (row & 15))) * 8 + (u32)(col & 7);

  // ---- Stage W_hh slice into LDS (once)
  {
    const us8* sh = (const us8*)(P.whh_hi + (size_t)jt16 * 32768);
    const us8* sl = (const us8*)(P.whh_lo + (size_t)jt16 * 32768);
    us8* dh = (us8*)lwhh_h;
    us8* dl = (us8*)lwhh_l;
#pragma unroll 2
    for (int i = threadIdx.x; i < 4096; i += 512) { dh[i] = sh[i]; dl[i] = sl[i]; }
    __syncthreads();
  }
  const u16* bhp = lwhh_h + kh * 8192 + lane * 8;
  const u16* blp = lwhh_l + kh * 8192 + lane * 8;

  // SINGLE-POLLER gate: wave0 polls all 128 same-rh producer flags
  // (32 lanes x dwordx4, one instruction per round); others wait at barrier.
  auto pollH = [&](const u32* flagbase, u32 need) {
    if (wv == 0) {
      const u32* p = flagbase + (lane & 31) * 4;
      for (;;) {
        u32x4 v;
        asm volatile("global_load_dwordx4 %0, %1, off sc0 sc1\n\ts_waitcnt vmcnt(0)"
                     : "=&v"(v) : "v"(p) : "memory");
        u32 mn = v.x < v.y ? v.x : v.y;
        u32 mn2 = v.z < v.w ? v.z : v.w;
        mn = mn < mn2 ? mn : mn2;
        if (__all(mn >= need)) break;
        __builtin_amdgcn_s_sleep(4);
      }
    }
    __syncthreads();
  };

  // publish: own stores ACKed -> block-wide sync -> release flag
  auto publish = [&](u32* flagarr, u32 val) {
    asm volatile("s_waitcnt vmcnt(0)" ::: "memory");
    __syncthreads();
    if (threadIdx.x == 0) st_agent_u32(flagarr + blk, val, 1);
  };

  u32 ebar = 0;
  // Global aggregation barrier (init only): slot release + all-block poll +
  // convergence max aggregation into red[8].
  auto bar_agg = [&]() {
    ++ebar;
    asm volatile("s_waitcnt vmcnt(0)" ::: "memory");
    __syncthreads();                                   // red[0..7] published
    if (wv == 0) {
      if (lane == 0) {
        float m = red[0];
#pragma unroll
        for (int w2 = 1; w2 < 8; ++w2) m = fmaxf(m, red[w2]);
        st_agent_u32(P.mslot + blk, __float_as_uint(m), 0);
        st_agent_u32(P.slots + blk, ebar, 1);  // release: orders mslot + hx stores
      }
      const u32* ps = P.slots + lane * 4;
      for (;;) {
        u32x4 pr;
        asm volatile("global_load_dwordx4 %0, %1, off sc0 sc1\n\ts_waitcnt vmcnt(0)"
                     : "=&v"(pr) : "v"(ps) : "memory");
        u32 mn = pr.x < pr.y ? pr.x : pr.y;
        u32 mn2 = pr.z < pr.w ? pr.z : pr.w;
        mn = mn < mn2 ? mn : mn2;
        if (__all(mn >= ebar)) break;
        __builtin_amdgcn_s_sleep(4);
      }
      float m = fmaxf(fmaxf(__uint_as_float(ld_agent_u32(P.mslot + lane * 4 + 0)),
                            __uint_as_float(ld_agent_u32(P.mslot + lane * 4 + 1))),
                      fmaxf(__uint_as_float(ld_agent_u32(P.mslot + lane * 4 + 2)),
                            __uint_as_float(ld_agent_u32(P.mslot + lane * 4 + 3))));
#pragma unroll
      for (int o = 32; o >= 1; o >>= 1) m = fmaxf(m, __shfl_down(m, o));
      if (lane == 0) ((u32*)red)[8] = (m <= 0.1f) ? 1u : 0u;
    }
    __syncthreads();
  };

  auto reduce_av = [&](f32x4 acc) -> float {
    rbuf[wv * 64 + lane] = acc;
    __syncthreads();
    const float* rb = (const float*)(rbuf + rg * 256);
    return rb[lane * 4 + kh] + rb[256 + lane * 4 + kh]
         + rb[512 + lane * 4 + kh] + rb[768 + lane * 4 + kh];
  };

  // main-scan cell GEMM: A hi via bypass loads, B hi+lo from LDS
  auto gemm_hi = [&](const u16* hx_in) -> float {
    const u16* ap = hx_in + bqg * 512 + kh * 32768 + lane * 8;
    u32x4 A0, A1, A2, A3, A4, A5, A6, A7, A8, A9, A10, A11, A12, A13, A14, A15;
    GLD16(ap, A);
    f32x4 z = {0.f, 0.f, 0.f, 0.f};
    f32x4 a0 = z, a1 = z, a2 = z, a3 = z;
#define HSTEP(c, AV) { bf16x8 bh_ = ld8(bhp + (c) * 512); bf16x8 bl_ = ld8(blp + (c) * 512); \
    bf16x8 ah_ = __builtin_bit_cast(bf16x8, AV); \
    if ((c) & 1) { a2 = mfma16(ah_, bh_, a2); a3 = mfma16(ah_, bl_, a3); } \
    else { a0 = mfma16(ah_, bh_, a0); a1 = mfma16(ah_, bl_, a1); } }
    HSTEP(0, A0)  HSTEP(1, A1)  HSTEP(2, A2)  HSTEP(3, A3)
    HSTEP(4, A4)  HSTEP(5, A5)  HSTEP(6, A6)  HSTEP(7, A7)
    HSTEP(8, A8)  HSTEP(9, A9)  HSTEP(10, A10) HSTEP(11, A11)
    HSTEP(12, A12) HSTEP(13, A13) HSTEP(14, A14) HSTEP(15, A15)
#undef HSTEP
    return reduce_av((a0 + a1) + (a2 + a3));
  };

  // init cell GEMM (fp32-faithful): bypass loads; same accumulator grouping
  auto gemm_hilo = [&](const u16* hx_in, const u16* hx_lo) -> float {
    const u16* aph = hx_in + bqg * 512 + kh * 32768 + lane * 8;
    const u16* apl = hx_lo + bqg * 512 + kh * 32768 + lane * 8;
    f32x4 z = {0.f, 0.f, 0.f, 0.f};
    f32x4 a0 = z, a1 = z, a2 = z, a3 = z, a4 = z, a5 = z;
    {
      u32x4 H0, H1, H2, H3, H4, H5, H6, H7, H8, H9, H10, H11, H12, H13, H14, H15;
      GLD16(aph, H);
#define ISTEP(c, AV) { bf16x8 bh_ = ld8(bhp + (c) * 512); bf16x8 bl_ = ld8(blp + (c) * 512); \
      bf16x8 ah_ = __builtin_bit_cast(bf16x8, AV); \
      if ((c) & 1) { a3 = mfma16(ah_, bh_, a3); a4 = mfma16(ah_, bl_, a4); } \
      else { a0 = mfma16(ah_, bh_, a0); a1 = mfma16(ah_, bl_, a1); } }
      ISTEP(0, H0)  ISTEP(1, H1)  ISTEP(2, H2)  ISTEP(3, H3)
      ISTEP(4, H4)  ISTEP(5, H5)  ISTEP(6, H6)  ISTEP(7, H7)
      ISTEP(8, H8)  ISTEP(9, H9)  ISTEP(10, H10) ISTEP(11, H11)
      ISTEP(12, H12) ISTEP(13, H13) ISTEP(14, H14) ISTEP(15, H15)
#undef ISTEP
    }
    {
      u32x4 L0, L1, L2, L3, L4, L5, L6, L7, L8, L9, L10, L11, L12, L13, L14, L15;
      GLD16(apl, L);
#define LSTEP(c, AV) { bf16x8 bh_ = ld8(bhp + (c) * 512); \
      bf16x8 al_ = __builtin_bit_cast(bf16x8, AV); \
      if ((c) & 1) { a5 = mfma16(al_, bh_, a5); } \
      else { a2 = mfma16(al_, bh_, a2); } }
      LSTEP(0, L0)  LSTEP(1, L1)  LSTEP(2, L2)  LSTEP(3, L3)
      LSTEP(4, L4)  LSTEP(5, L5)  LSTEP(6, L6)  LSTEP(7, L7)
      LSTEP(8, L8)  LSTEP(9, L9)  LSTEP(10, L10) LSTEP(11, L11)
      LSTEP(12, L12) LSTEP(13, L13) LSTEP(14, L14) LSTEP(15, L15)
#undef LSTEP
    }
    return reduce_av(((a0 + a1) + (a2 + a3)) + (a4 + a5));
  };

  auto make_noise = [&](U2 key) -> float {
    U2 o = tf2x32(key, U2{0u, idx});
    return jax_normal(o.x ^ o.y);
  };

  const float NS = 0.15811388300841897f;
  const float xv0 = P.xpj[col];
  const float xv1 = P.xpj[H_N + col];

  u16* hxs[3]  = {P.hx0, P.hx1, P.hx2};
  u16* hxls[3] = {P.hx0l, P.hx1l, P.hx2l};
  int i0 = 0, i1 = 1, i2 = 2;
  float hp0 = 0.f;
  int stable = 0;
  float nzA = make_noise(P.ka[0]);
  float nzB = 0.f;

  const u32* iflags = P.initflag + rh * 128;
  const u32* sflags = P.scanflag + rh * 128;

  // ---- init loop: cell1 -> flag publish / single-poller gate -> cell2 -> agg
#pragma unroll 1
  for (int it = 0; it < 100; ++it) {
    float av = gemm_hilo(hxs[i0], hxls[i0]);
    float pre = av + xv0 + NS * nzA;
    float hp1 = 0.8f * hp0 + 0.2f * fmaxf(pre, 0.f);
    { u16 hb = f2bf(hp1);
      st_agent_u16(hxs[i1] + xoff, hb);
      st_agent_u16(hxls[i1] + xoff, f2bf(hp1 - bf2f(hb))); }
    publish(P.initflag, (u32)(it + 1));
    nzB = make_noise(P.kb[it]);      // hides flag RTT (wave0 polls meanwhile)
    pollH(iflags, (u32)(it + 1));    // all 128 same-rh producers wrote i1

    av = gemm_hilo(hxs[i1], hxls[i1]);
    pre = av + xv1 + NS * nzB;
    float hp2 = 0.8f * hp1 + 0.2f * fmaxf(pre, 0.f);
    { u16 hb = f2bf(hp2);
      st_agent_u16(hxs[i2] + xoff, hb);
      st_agent_u16(hxls[i2] + xoff, f2bf(hp2 - bf2f(hb))); }
    float lmax = fabsf(hp2 - hp0);
#pragma unroll
    for (int off = 32; off >= 1; off >>= 1)
      lmax = fmaxf(lmax, __shfl_down(lmax, off));
    if (lane == 0) red[wv] = lmax;
    nzA = make_noise(P.ka[it + 1]);  // hides store ack
    bar_agg();                       // global: orders i2 writes + convergence

    bool close = (((u32*)red)[8] & 1u) != 0u;
    if (close) {
      if (++stable >= 4) break;
    } else stable = 0;
    int tmp = i0; i0 = i2; i2 = tmp;   // h0 <- h2
    hp0 = hp2;
  }

  // ---- main scan: pure dataflow, 3 rotating buffers, single-poller gates.
  // flag semantics: scanflag[blk] = s+1  <=>  block wrote h_s to bufs[s%3].
  u16* bufs[3] = {P.hxS0, P.hxS1, P.hxS2};
  st_agent_u16(bufs[0] + xoff, f2bf(hp0));   // publish h0
  publish(P.scanflag, 1u);
  float nzS = make_noise(P.ks[0]);
  float xv = P.hidden[idx];
  float hp = hp0;
#pragma unroll 1
  for (int t = 0; t < T_N; ++t) {
    pollH(sflags, (u32)(t + 1));             // h_t available from producers
    float av = gemm_hi(bufs[t % 3]);
    float pre = av + xv + NS * nzS;
    float hn = 0.8f * hp + 0.2f * fmaxf(pre, 0.f);
    hp = hn;
    if (t != T_N - 1) {
      st_agent_u16(bufs[(t + 1) % 3] + xoff, f2bf(hn));
      publish(P.scanflag, (u32)(t + 2));
      P.hidden[(size_t)t * BH + idx] = hn;   // off the pre-release ack path
      nzS = make_noise(P.ks[t + 1]);         // hides flag RTT
      xv = P.hidden[(size_t)(t + 1) * BH + idx];
    } else {
      P.hidden[(size_t)t * BH + idx] = hn;
    }
  }
}

// ---- output GEMM: out[M=16384][256] = hidden(bf16) @ Wout^T (hi+lo)
__global__ void __launch_bounds__(256) out_gemm(const float* __restrict__ hidden,
    const u16* __restrict__ wo_hi, const u16* __restrict__ wo_lo, float* __restrict__ out) {
  int lane = threadIdx.x & 63, wv = threadIdx.x >> 6;
  int mb = blockIdx.x * 64 + wv * 16;
  int arow = mb + (lane & 15);
  int q = lane >> 4;
  f32x4 acc[16];
#pragma unroll
  for (int n = 0; n < 16; ++n) acc[n] = {0.f, 0.f, 0.f, 0.f};
  const float* ap = hidden + (size_t)arow * H_N + q * 8;
#pragma unroll 2
  for (int c = 0; c < 64; ++c) {
    const float4* a4 = reinterpret_cast<const float4*>(ap + c * 32);
    float4 f0 = a4[0], f1 = a4[1];
    us8 av;
    av[0] = f2bf(f0.x); av[1] = f2bf(f0.y); av[2] = f2bf(f0.z); av[3] = f2bf(f0.w);
    av[4] = f2bf(f1.x); av[5] = f2bf(f1.y); av[6] = f2bf(f1.z); av[7] = f2bf(f1.w);
    bf16x8 a = __builtin_bit_cast(bf16x8, av);
#pragma unroll
    for (int n = 0; n < 16; ++n) {
      bf16x8 bh = ld8(wo_hi + ((size_t)(n * 64 + c) * 64 + lane) * 8);
      bf16x8 bl = ld8(wo_lo + ((size_t)(n * 64 + c) * 64 + lane) * 8);
      acc[n] = mfma16(a, bh, acc[n]);
      acc[n] = mfma16(a, bl, acc[n]);
    }
  }
#pragma unroll
  for (int n = 0; n < 16; ++n)
#pragma unroll
    for (int r = 0; r < 4; ++r)
      out[(size_t)(mb + q * 4 + r) * NOUT_N + n * 16 + (lane & 15)] = acc[n][r];
}

extern "C" void kernel_launch(void* const* d_in, const int* in_sizes, int n_in,
                              void* d_out, int out_size, void* d_ws, size_t ws_size,
                              hipStream_t stream) {
  const float* x = (const float*)d_in[0];
  const float* W_ih = (const float*)d_in[1];
  const float* W_hh = (const float*)d_in[2];
  const float* bias = (const float*)d_in[3];
  const float* W_out = (const float*)d_in[4];
  float* out = (float*)d_out;

  char* ws = (char*)d_ws;
  size_t off = 0;
  auto alloc = [&](size_t bytes) -> void* {
    void* p = ws + off;
    off += (bytes + 255) & ~(size_t)255;
    return p;
  };
  u16* whh_hi = (u16*)alloc(8388608);
  u16* whh_lo = (u16*)alloc(8388608);
  u16* wih_hi = (u16*)alloc(1048576);
  u16* wih_lo = (u16*)alloc(1048576);
  u16* wout_hi = (u16*)alloc(1048576);
  u16* wout_lo = (u16*)alloc(1048576);
  u16* xp_hi = (u16*)alloc(8388608);
  u16* xp_lo = (u16*)alloc(8388608);
  float* xpj = (float*)alloc(16384);
  u16* hx0 = (u16*)alloc(262144);
  u16* hx1 = (u16*)alloc(262144);
  u16* hx2 = (u16*)alloc(262144);
  u16* hx0l = (u16*)alloc(262144);
  u16* hx1l = (u16*)alloc(262144);
  u16* hx2l = (u16*)alloc(262144);
  u16* hxS0 = (u16*)alloc(262144);
  u16* hxS1 = (u16*)alloc(262144);
  u16* hxS2 = (u16*)alloc(262144);
  U2* ka = (U2*)alloc(832);
  U2* kb = (U2*)alloc(832);
  U2* ks = (U2*)alloc(2048);
  u32* bar = (u32*)alloc(4096);

  float* hidden = out + OUT_SZ;

  hipLaunchKernelGGL(pack_b_kernel, dim3(2048), dim3(256), 0, stream, W_hh, whh_hi, whh_lo, 2048, 6);
  hipLaunchKernelGGL(pack_b_kernel, dim3(256), dim3(256), 0, stream, W_ih, wih_hi, wih_lo, 256, 3);
  hipLaunchKernelGGL(pack_b_kernel, dim3(256), dim3(256), 0, stream, W_out, wout_hi, wout_lo, 2048, 6);
  hipLaunchKernelGGL(pack_x_kernel, dim3(2048), dim3(256), 0, stream, x, xp_hi, xp_lo);
  hipLaunchKernelGGL(probe_proj, dim3(16), dim3(256), 0, stream, x, W_ih, bias, xpj);
  hipLaunchKernelGGL(setup_keys, dim3(1), dim3(256), 0, stream, ka, kb, ks);
  hipLaunchKernelGGL(zero_bufs, dim3(256), dim3(256), 0, stream, (u32*)hx0, (u32*)hx0l, bar);
  hipLaunchKernelGGL(xproj_gemm, dim3(32768), dim3(256), 0, stream, xp_hi, xp_lo, wih_hi, wih_lo, bias, hidden);

  RnnParams P;
  P.whh_hi = whh_hi; P.whh_lo = whh_lo;
  P.xpj = xpj;
  P.hidden = hidden;
  P.hx0 = hx0; P.hx1 = hx1; P.hx2 = hx2;
  P.hx0l = hx0l; P.hx1l = hx1l; P.hx2l = hx2l;
  P.hxS0 = hxS0; P.hxS1 = hxS1; P.hxS2 = hxS2;
  P.ka = ka; P.kb = kb; P.ks = ks;
  P.slots = bar; P.mslot = bar + 256;
  P.initflag = bar + 512; P.scanflag = bar + 768;

  static bool attr_set = false;
  if (!attr_set) {
    hipFuncSetAttribute((const void*)rnn_persistent,
                        hipFuncAttributeMaxDynamicSharedMemorySize, LDS_BYTES);
    attr_set = true;
  }

  void* kargs[] = {(void*)&P};
  hipLaunchCooperativeKernel((const void*)rnn_persistent, dim3(256), dim3(512), kargs, LDS_BYTES, stream);

  hipLaunchKernelGGL(out_gemm, dim3(256), dim3(256), 0, stream, hidden, wout_hi, wout_lo, out);
}

// Round 11
// 4811.871 us; speedup vs baseline: 1.2971x; 1.0644x over previous
//
#include <hip/hip_runtime.h>

typedef unsigned int u32;
typedef unsigned short u16;
typedef __bf16 bf16x8 __attribute__((ext_vector_type(8)));
typedef u16 us8 __attribute__((ext_vector_type(8)));
typedef u32 u32x4 __attribute__((ext_vector_type(4)));
typedef float f32x4 __attribute__((ext_vector_type(4)));

#define T_N 256
#define B_N 64
#define NIN_N 256
#define H_N 2048
#define NOUT_N 256
#define BH (B_N * H_N)            // 131072
#define OUT_SZ (T_N * B_N * NOUT_N) // 4194304

// LDS: W_hi [2cs][64c][512] 128KB | rbuf [8ke][2cs][64 lane] f32x4 16KB | red 64B
#define LDS_W    0
#define LDS_RBUF 131072
#define LDS_RED  147456
#define LDS_BYTES 147520

struct U2 { u32 x, y; };

__device__ __forceinline__ u32 rotl32(u32 v, int r) { return (v << r) | (v >> (32 - r)); }

// JAX threefry-2x32, 20 rounds
__device__ __forceinline__ U2 tf2x32(U2 k, U2 x) {
  u32 ks0 = k.x, ks1 = k.y, ks2 = k.x ^ k.y ^ 0x1BD11BDAu;
  x.x += ks0; x.y += ks1;
#define TFR(a) x.x += x.y; x.y = rotl32(x.y,(a)); x.y ^= x.x;
  TFR(13) TFR(15) TFR(26) TFR(6)
  x.x += ks1; x.y += ks2 + 1u;
  TFR(17) TFR(29) TFR(16) TFR(24)
  x.x += ks2; x.y += ks0 + 2u;
  TFR(13) TFR(15) TFR(26) TFR(6)
  x.x += ks0; x.y += ks1 + 3u;
  TFR(17) TFR(29) TFR(16) TFR(24)
  x.x += ks1; x.y += ks2 + 4u;
  TFR(13) TFR(15) TFR(26) TFR(6)
  x.x += ks2; x.y += ks0 + 5u;
#undef TFR
  return x;
}

// JAX normal: uniform in [-1+2^-24, 1) -> sqrt(2)*erfinv (XLA f32 Giles polynomial)
__device__ __forceinline__ float jax_normal(u32 bits) {
  float f = __uint_as_float((bits >> 9) | 0x3f800000u) - 1.0f;
  const float lo = -0.99999994f;
  float u = fmaf(f, 2.0f, lo);
  u = fmaxf(u, lo);
  float w = -log1pf(-u * u);
  float p;
  if (w < 5.0f) {
    w = w - 2.5f;
    p =            2.81022636e-08f;
    p = fmaf(p, w, 3.43273939e-07f);
    p = fmaf(p, w, -3.5233877e-06f);
    p = fmaf(p, w, -4.39150654e-06f);
    p = fmaf(p, w, 0.00021858087f);
    p = fmaf(p, w, -0.00125372503f);
    p = fmaf(p, w, -0.00417768164f);
    p = fmaf(p, w, 0.246640727f);
    p = fmaf(p, w, 1.50140941f);
  } else {
    w = sqrtf(w) - 3.0f;
    p =            -0.000200214257f;
    p = fmaf(p, w, 0.000100950558f);
    p = fmaf(p, w, 0.00134934322f);
    p = fmaf(p, w, -0.00367342844f);
    p = fmaf(p, w, 0.00573950773f);
    p = fmaf(p, w, -0.0076224613f);
    p = fmaf(p, w, 0.00943887047f);
    p = fmaf(p, w, 1.00167406f);
    p = fmaf(p, w, 2.83297682f);
  }
  return 1.41421354f * (p * u);
}

__device__ __forceinline__ u16 f2bf(float f) {
  u32 x = __float_as_uint(f);
  u32 r = (x + 0x7FFFu + ((x >> 16) & 1u)) >> 16;
  return (u16)r;
}
__device__ __forceinline__ float bf2f(u16 b) { return __uint_as_float(((u32)b) << 16); }

__device__ __forceinline__ bf16x8 ld8(const u16* p) {
  us8 v = *reinterpret_cast<const us8*>(p);
  return __builtin_bit_cast(bf16x8, v);
}
__device__ __forceinline__ f32x4 mfma16(bf16x8 a, bf16x8 b, f32x4 c) {
  return __builtin_amdgcn_mfma_f32_16x16x32_bf16(a, b, c, 0, 0, 0);
}

// agent-scope (sc0 sc1) helpers: write-through to / read from die-level MALL
__device__ __forceinline__ void st_agent_u16(u16* p, u16 v) {
  __hip_atomic_store(p, v, __ATOMIC_RELAXED, __HIP_MEMORY_SCOPE_AGENT);
}
__device__ __forceinline__ void st_agent_u32(u32* p, u32 v, int order) {
  if (order) __hip_atomic_store(p, v, __ATOMIC_RELEASE, __HIP_MEMORY_SCOPE_AGENT);
  else       __hip_atomic_store(p, v, __ATOMIC_RELAXED, __HIP_MEMORY_SCOPE_AGENT);
}
__device__ __forceinline__ u32 ld_agent_u32(const u32* p) {
  return __hip_atomic_load(p, __ATOMIC_RELAXED, __HIP_MEMORY_SCOPE_AGENT);
}

// 8 coherent bypass 16B loads: chunks j=0..7 at AP + j*2048 u16
#define GLD8(AP, V) \
  asm volatile( \
    "global_load_dwordx4 %0, %8, off offset:-4096 sc0 sc1\n\t" \
    "global_load_dwordx4 %1, %8, off sc0 sc1\n\t" \
    "global_load_dwordx4 %2, %9, off offset:-4096 sc0 sc1\n\t" \
    "global_load_dwordx4 %3, %9, off sc0 sc1\n\t" \
    "global_load_dwordx4 %4, %10, off offset:-4096 sc0 sc1\n\t" \
    "global_load_dwordx4 %5, %10, off sc0 sc1\n\t" \
    "global_load_dwordx4 %6, %11, off offset:-4096 sc0 sc1\n\t" \
    "global_load_dwordx4 %7, %11, off sc0 sc1\n\t" \
    "s_waitcnt vmcnt(0)" \
    : "=&v"(V##0), "=&v"(V##1), "=&v"(V##2), "=&v"(V##3), \
      "=&v"(V##4), "=&v"(V##5), "=&v"(V##6), "=&v"(V##7) \
    : "v"(AP + 2048), "v"(AP + 3 * 2048), "v"(AP + 5 * 2048), "v"(AP + 7 * 2048) \
    : "memory")

// 8 hi + 8 lo bypass loads, single vmcnt
#define GLD8HL(APH, APL, V, W) \
  asm volatile( \
    "global_load_dwordx4 %0, %16, off offset:-4096 sc0 sc1\n\t" \
    "global_load_dwordx4 %1, %16, off sc0 sc1\n\t" \
    "global_load_dwordx4 %2, %17, off offset:-4096 sc0 sc1\n\t" \
    "global_load_dwordx4 %3, %17, off sc0 sc1\n\t" \
    "global_load_dwordx4 %4, %18, off offset:-4096 sc0 sc1\n\t" \
    "global_load_dwordx4 %5, %18, off sc0 sc1\n\t" \
    "global_load_dwordx4 %6, %19, off offset:-4096 sc0 sc1\n\t" \
    "global_load_dwordx4 %7, %19, off sc0 sc1\n\t" \
    "global_load_dwordx4 %8, %20, off offset:-4096 sc0 sc1\n\t" \
    "global_load_dwordx4 %9, %20, off sc0 sc1\n\t" \
    "global_load_dwordx4 %10, %21, off offset:-4096 sc0 sc1\n\t" \
    "global_load_dwordx4 %11, %21, off sc0 sc1\n\t" \
    "global_load_dwordx4 %12, %22, off offset:-4096 sc0 sc1\n\t" \
    "global_load_dwordx4 %13, %22, off sc0 sc1\n\t" \
    "global_load_dwordx4 %14, %23, off offset:-4096 sc0 sc1\n\t" \
    "global_load_dwordx4 %15, %23, off sc0 sc1\n\t" \
    "s_waitcnt vmcnt(0)" \
    : "=&v"(V##0), "=&v"(V##1), "=&v"(V##2), "=&v"(V##3), \
      "=&v"(V##4), "=&v"(V##5), "=&v"(V##6), "=&v"(V##7), \
      "=&v"(W##0), "=&v"(W##1), "=&v"(W##2), "=&v"(W##3), \
      "=&v"(W##4), "=&v"(W##5), "=&v"(W##6), "=&v"(W##7) \
    : "v"(APH + 2048), "v"(APH + 3 * 2048), "v"(APH + 5 * 2048), "v"(APH + 7 * 2048), \
      "v"(APL + 2048), "v"(APL + 3 * 2048), "v"(APL + 5 * 2048), "v"(APL + 7 * 2048) \
    : "memory")

// ---- Pack B-operand (W rows along n-dim): [R/16 tiles][K/32 chunks][64 lanes][8 bf16]
__global__ void __launch_bounds__(256) pack_b_kernel(const float* __restrict__ W,
    u16* __restrict__ hi, u16* __restrict__ lo, int K, int Cshift) {
  int tid = blockIdx.x * 256 + threadIdx.x;
  int lane = tid & 63;
  size_t tile = tid >> 6;
  int C = 1 << Cshift;
  int jt = (int)(tile >> Cshift), c = (int)(tile & (C - 1));
  int row = jt * 16 + (lane & 15);
  int k0 = c * 32 + (lane >> 4) * 8;
  const float* src = W + (size_t)row * K + k0;
  us8 vh, vl;
#pragma unroll
  for (int j = 0; j < 8; ++j) {
    float w = src[j];
    u16 hb = f2bf(w);
    vh[j] = hb;
    vl[j] = f2bf(w - bf2f(hb));
  }
  *reinterpret_cast<us8*>(hi + tile * 512 + lane * 8) = vh;
  *reinterpret_cast<us8*>(lo + tile * 512 + lane * 8) = vl;
}

// ---- Pack x (A-operand) per t
__global__ void __launch_bounds__(256) pack_x_kernel(const float* __restrict__ x,
    u16* __restrict__ hi, u16* __restrict__ lo) {
  int tid = blockIdx.x * 256 + threadIdx.x; // 524288
  int t = tid >> 11;
  int r = tid & 2047;
  int lane = r & 63, piece = r >> 6; // 0..31
  int c = piece >> 2, g = piece & 3;
  int row = g * 16 + (lane & 15);
  int k0 = c * 32 + (lane >> 4) * 8;
  const float* src = x + (size_t)t * (B_N * NIN_N) + (size_t)row * NIN_N + k0;
  us8 vh, vl;
#pragma unroll
  for (int j = 0; j < 8; ++j) {
    float w = src[j];
    u16 hb = f2bf(w);
    vh[j] = hb;
    vl[j] = f2bf(w - bf2f(hb));
  }
  size_t off = (size_t)t * 16384 + (size_t)piece * 512 + lane * 8;
  *reinterpret_cast<us8*>(hi + off) = vh;
  *reinterpret_cast<us8*>(lo + off) = vl;
}

// ---- Probe projections: xpj[p][col] = x[p][0][:] . W_ih[col][:] + b[col], f32
__global__ void __launch_bounds__(256) probe_proj(const float* __restrict__ x,
    const float* __restrict__ Wih, const float* __restrict__ bias, float* __restrict__ xpj) {
  int g = blockIdx.x * 256 + threadIdx.x;   // 4096
  int p = g >> 11, col = g & 2047;
  const float* xr = x + (size_t)p * (B_N * NIN_N);
  const float* wr = Wih + (size_t)col * NIN_N;
  float s = 0.f;
#pragma unroll 4
  for (int k = 0; k < NIN_N; ++k) s = fmaf(xr[k], wr[k], s);
  xpj[p * H_N + col] = s + bias[col];
}

// ---- xproj GEMM: hidden[t*BH + row*H + col] = x[t][row][:] . W_ih[col][:] + b[col]
__global__ void __launch_bounds__(256) xproj_gemm(const u16* __restrict__ xp_hi,
    const u16* __restrict__ xp_lo, const u16* __restrict__ wih_hi,
    const u16* __restrict__ wih_lo, const float* __restrict__ bias,
    float* __restrict__ xout) {
  int lane = threadIdx.x & 63, wvq = threadIdx.x >> 6;
  int t = blockIdx.x >> 7, jt16 = blockIdx.x & 127;
  const u16* ah = xp_hi + (size_t)t * 16384 + wvq * 512 + lane * 8;
  const u16* al = xp_lo + (size_t)t * 16384 + wvq * 512 + lane * 8;
  const u16* bh = wih_hi + (size_t)jt16 * 4096 + lane * 8;
  const u16* bl = wih_lo + (size_t)jt16 * 4096 + lane * 8;
  f32x4 z = {0.f, 0.f, 0.f, 0.f};
  f32x4 a0 = z, a1 = z, a2 = z;
#pragma unroll
  for (int c = 0; c < 8; ++c) {
    bf16x8 xh = ld8(ah + c * 2048), xl = ld8(al + c * 2048);
    bf16x8 wh = ld8(bh + c * 512),  wl = ld8(bl + c * 512);
    a0 = mfma16(xh, wh, a0);
    a1 = mfma16(xh, wl, a1);
    a2 = mfma16(xl, wh, a2);
  }
  f32x4 acc = (a0 + a1) + a2;
  int col = jt16 * 16 + (lane & 15);
  int q = lane >> 4;
  float bc = bias[col];
#pragma unroll
  for (int r = 0; r < 4; ++r) {
    int row = wvq * 16 + q * 4 + r;
    xout[(size_t)t * BH + (size_t)row * H_N + col] = acc[r] + bc;
  }
}

// ---- Keys (PARTITIONABLE threefry semantics)
__global__ void setup_keys(U2* ka, U2* kb, U2* ks) {
  int i = threadIdx.x;
  U2 base{0u, 42u};
  if (i < 104) {
    U2 ki = tf2x32(base, U2{0u, (u32)i});
    ka[i] = tf2x32(ki, U2{0u, 0u});
    kb[i] = tf2x32(ki, U2{0u, 1u});
  }
  U2 km = tf2x32(base, U2{0u, 1000000u});
  ks[i] = tf2x32(km, U2{0u, (u32)i});   // i in 0..255
}

__global__ void __launch_bounds__(256) zero_bufs(u32* hx0w, u32* hx0lw, u32* bar) {
  int g = blockIdx.x * 256 + threadIdx.x;   // 65536
  if (g < BH / 2) { hx0w[g] = 0u; hx0lw[g] = 0u; }
  if (g < 1024) bar[g] = 0u;
}

struct RnnParams {
  const u16 *whh_hi, *whh_lo;
  const float* xpj;          // [2][H] probe projections (+bias)
  float* hidden;             // = outbuf + OUT_SZ; pre-filled with xproj (+bias)
  u16 *hx0, *hx1, *hx2;      // init h (hi) buffers
  u16 *hx0l, *hx1l, *hx2l;   // init h (lo) buffers
  u16 *hxS0, *hxS1, *hxS2;   // scan rotating h buffers (3-deep)
  const U2 *ka, *kb, *ks;
  u32 *slots, *mslot;        // agg barrier: [256] epochs, [256] max bits
  u32 *initflag, *scanflag;  // [256] monotonic producer flags
};

// 16-ROW tiling: 256 blocks x 512 threads, 1 block/CU.
// block = (bg 0..3: 16-row batch group) x (ct 0..63: 32-col tile).
// wave = ke (0..7: K-eighth, 256 K). Each wave computes BOTH 16-col subtiles
// over its K-eighth -> per-block A-read = 16 rows x 2048 K = 64 KB (half of
// the 32-row tiling). W_hi slice (128KB) in LDS; W_lo (128KB) via NORMAL
// CACHED loads (read-only -> L2-resident, off the MALL path). Sync: per-wave
// dataflow — wave ke polls its 8 producer blocks (ct' = ke*8..+8) then loads.
__global__ void __launch_bounds__(512) rnn_persistent(RnnParams P) {
  extern __shared__ char smem[];
  u16* lW = (u16*)(smem + LDS_W);            // [2 cs][64 c][64 lane][8]
  f32x4* rbuf = (f32x4*)(smem + LDS_RBUF);   // [(ke*2+cs)*64 + lane]
  float* red  = (float*)(smem + LDS_RED);    // [0..7] wave maxes, [8] flag word

  const int tid = threadIdx.x;
  const int lane = tid & 63;
  const int wv = tid >> 6;       // = ke, 0..7
  const int ke = wv;
  const int cs_own = wv >> 2;    // epilogue: col subtile
  const int r_own = wv & 3;      // epilogue: row-within-4
  const int blk = blockIdx.x;
  const int bg = blk >> 6;       // 16-row batch group 0..3
  const int ct = blk & 63;       // 32-col tile 0..63
  const int row = bg * 16 + (lane >> 4) * 4 + r_own;
  const int col = ct * 32 + cs_own * 16 + (lane & 15);
  const u32 idx = (u32)row * H_N + (u32)col;
  const u32 xoff = ((u32)((col >> 5) * 4 + (row >> 4)) * 64
                    + (u32)(((col >> 3) & 3) * 16 + (row & 15))) * 8 + (u32)(col & 7);

  // ---- Stage W_hi slice into LDS (once): [cs][c][lane][8]
  {
    const us8* src = (const us8*)P.whh_hi;
    us8* dst = (us8*)lW;
#pragma unroll 4
    for (int i = tid; i < 8192; i += 512) {
      int cs_ = i >> 12, rem = i & 4095;
      dst[i] = src[(size_t)(ct * 2 + cs_) * 4096 + rem];
    }
    __syncthreads();
  }
  const u16* lwb0 = lW + ke * 4096 + lane * 8;
  const u16* lwb1 = lW + 32768 + ke * 4096 + lane * 8;
  const u16* wlo0 = P.whh_lo + (size_t)(ct * 2 + 0) * 32768 + ke * 4096 + lane * 8;
  const u16* wlo1 = P.whh_lo + (size_t)(ct * 2 + 1) * 32768 + ke * 4096 + lane * 8;

  // per-wave producer flags: 8 blocks (bg, ct' = ke*8 .. ke*8+8)
  const u32* ifw = P.initflag + bg * 64 + ke * 8;
  const u32* sfw = P.scanflag + bg * 64 + ke * 8;

  // per-wave poll of 8 producer flags (no block barrier needed)
  auto pollW = [&](const u32* fw, u32 need) {
    const u32* p = fw + (lane & 7);
    for (;;) {
      u32 v;
      asm volatile("global_load_dword %0, %1, off sc0 sc1\n\ts_waitcnt vmcnt(0)"
                   : "=v"(v) : "v"(p) : "memory");
      if (__all(v >= need)) break;
      __builtin_amdgcn_s_sleep(1);
    }
  };

  // publish: own stores ACKed -> block-wide sync -> release flag
  auto publish = [&](u32* flagarr, u32 val) {
    asm volatile("s_waitcnt vmcnt(0)" ::: "memory");
    __syncthreads();
    if (tid == 0) st_agent_u32(flagarr + blk, val, 1);
  };

  u32 ebar = 0;
  // Global aggregation barrier (init only)
  auto bar_agg = [&]() {
    ++ebar;
    asm volatile("s_waitcnt vmcnt(0)" ::: "memory");
    __syncthreads();                                   // red[0..7] published
    if (wv == 0) {
      if (lane == 0) {
        float m = red[0];
#pragma unroll
        for (int w2 = 1; w2 < 8; ++w2) m = fmaxf(m, red[w2]);
        st_agent_u32(P.mslot + blk, __float_as_uint(m), 0);
        st_agent_u32(P.slots + blk, ebar, 1);  // release: orders mslot + hx stores
      }
      const u32* ps = P.slots + lane * 4;
      for (;;) {
        u32x4 pr;
        asm volatile("global_load_dwordx4 %0, %1, off sc0 sc1\n\ts_waitcnt vmcnt(0)"
                     : "=&v"(pr) : "v"(ps) : "memory");
        u32 mn = pr.x < pr.y ? pr.x : pr.y;
        u32 mn2 = pr.z < pr.w ? pr.z : pr.w;
        mn = mn < mn2 ? mn : mn2;
        if (__all(mn >= ebar)) break;
        __builtin_amdgcn_s_sleep(1);
      }
      float m = fmaxf(fmaxf(__uint_as_float(ld_agent_u32(P.mslot + lane * 4 + 0)),
                            __uint_as_float(ld_agent_u32(P.mslot + lane * 4 + 1))),
                      fmaxf(__uint_as_float(ld_agent_u32(P.mslot + lane * 4 + 2)),
                            __uint_as_float(ld_agent_u32(P.mslot + lane * 4 + 3))));
#pragma unroll
      for (int o = 32; o >= 1; o >>= 1) m = fmaxf(m, __shfl_down(m, o));
      if (lane == 0) ((u32*)red)[8] = (m <= 0.1f) ? 1u : 0u;
    }
    __syncthreads();
  };

  // reduce across 8 K-eighths: rbuf store, sync, fixed ascending-ke sum
  auto reduce_sum = [&](f32x4 o0, f32x4 o1) -> float {
    rbuf[(wv * 2 + 0) * 64 + lane] = o0;
    rbuf[(wv * 2 + 1) * 64 + lane] = o1;
    __syncthreads();
    const float* rb = (const float*)rbuf;
    int o = cs_own * 256 + lane * 4 + r_own;
    float av = rb[o];
    av += rb[o + 512];  av += rb[o + 1024]; av += rb[o + 1536];
    av += rb[o + 2048]; av += rb[o + 2560]; av += rb[o + 3072]; av += rb[o + 3584];
    return av;
  };

  // scan cell GEMM: A hi bypass (GLD8), W hi from LDS + lo cached; both cs
  auto gemm_sc = [&](const u16* hx_in, f32x4& o0, f32x4& o1) {
    const u16* ap = hx_in + bg * 512 + ke * 16384 + lane * 8;
    u32x4 A0, A1, A2, A3, A4, A5, A6, A7;
    GLD8(ap, A);
    f32x4 z = {0.f, 0.f, 0.f, 0.f};
    {
      f32x4 a0 = z, a1 = z, a2 = z, a3 = z;
#define SSTEP(j, AV) { bf16x8 bh_ = ld8(lwb0 + (j) * 512); bf16x8 bl_ = ld8(wlo0 + (j) * 512); \
      bf16x8 ah_ = __builtin_bit_cast(bf16x8, AV); \
      if ((j) & 1) { a2 = mfma16(ah_, bh_, a2); a3 = mfma16(ah_, bl_, a3); } \
      else { a0 = mfma16(ah_, bh_, a0); a1 = mfma16(ah_, bl_, a1); } }
      SSTEP(0, A0) SSTEP(1, A1) SSTEP(2, A2) SSTEP(3, A3)
      SSTEP(4, A4) SSTEP(5, A5) SSTEP(6, A6) SSTEP(7, A7)
#undef SSTEP
      o0 = (a0 + a1) + (a2 + a3);
    }
    {
      f32x4 a0 = z, a1 = z, a2 = z, a3 = z;
#define SSTEP(j, AV) { bf16x8 bh_ = ld8(lwb1 + (j) * 512); bf16x8 bl_ = ld8(wlo1 + (j) * 512); \
      bf16x8 ah_ = __builtin_bit_cast(bf16x8, AV); \
      if ((j) & 1) { a2 = mfma16(ah_, bh_, a2); a3 = mfma16(ah_, bl_, a3); } \
      else { a0 = mfma16(ah_, bh_, a0); a1 = mfma16(ah_, bl_, a1); } }
      SSTEP(0, A0) SSTEP(1, A1) SSTEP(2, A2) SSTEP(3, A3)
      SSTEP(4, A4) SSTEP(5, A5) SSTEP(6, A6) SSTEP(7, A7)
#undef SSTEP
      o1 = (a0 + a1) + (a2 + a3);
    }
  };

  // init cell GEMM (fp32-faithful): A hi+lo bypass, both cs
  auto gemm_in = [&](const u16* hxh, const u16* hxl, f32x4& o0, f32x4& o1) {
    const u16* aph = hxh + bg * 512 + ke * 16384 + lane * 8;
    const u16* apl = hxl + bg * 512 + ke * 16384 + lane * 8;
    u32x4 H0, H1, H2, H3, H4, H5, H6, H7, L0, L1, L2, L3, L4, L5, L6, L7;
    GLD8HL(aph, apl, H, L);
    f32x4 z = {0.f, 0.f, 0.f, 0.f};
    {
      f32x4 a0 = z, a1 = z, a2 = z, a3 = z, a4 = z, a5 = z;
#define ISTEP(j, AV, LV) { bf16x8 bh_ = ld8(lwb0 + (j) * 512); bf16x8 bl_ = ld8(wlo0 + (j) * 512); \
      bf16x8 ah_ = __builtin_bit_cast(bf16x8, AV); bf16x8 al_ = __builtin_bit_cast(bf16x8, LV); \
      if ((j) & 1) { a3 = mfma16(ah_, bh_, a3); a4 = mfma16(ah_, bl_, a4); a5 = mfma16(al_, bh_, a5); } \
      else { a0 = mfma16(ah_, bh_, a0); a1 = mfma16(ah_, bl_, a1); a2 = mfma16(al_, bh_, a2); } }
      ISTEP(0, H0, L0) ISTEP(1, H1, L1) ISTEP(2, H2, L2) ISTEP(3, H3, L3)
      ISTEP(4, H4, L4) ISTEP(5, H5, L5) ISTEP(6, H6, L6) ISTEP(7, H7, L7)
#undef ISTEP
      o0 = ((a0 + a1) + (a2 + a3)) + (a4 + a5);
    }
    {
      f32x4 a0 = z, a1 = z, a2 = z, a3 = z, a4 = z, a5 = z;
#define ISTEP(j, AV, LV) { bf16x8 bh_ = ld8(lwb1 + (j) * 512); bf16x8 bl_ = ld8(wlo1 + (j) * 512); \
      bf16x8 ah_ = __builtin_bit_cast(bf16x8, AV); bf16x8 al_ = __builtin_bit_cast(bf16x8, LV); \
      if ((j) & 1) { a3 = mfma16(ah_, bh_, a3); a4 = mfma16(ah_, bl_, a4); a5 = mfma16(al_, bh_, a5); } \
      else { a0 = mfma16(ah_, bh_, a0); a1 = mfma16(ah_, bl_, a1); a2 = mfma16(al_, bh_, a2); } }
      ISTEP(0, H0, L0) ISTEP(1, H1, L1) ISTEP(2, H2, L2) ISTEP(3, H3, L3)
      ISTEP(4, H4, L4) ISTEP(5, H5, L5) ISTEP(6, H6, L6) ISTEP(7, H7, L7)
#undef ISTEP
      o1 = ((a0 + a1) + (a2 + a3)) + (a4 + a5);
    }
  };

  auto make_noise = [&](U2 key) -> float {
    U2 o = tf2x32(key, U2{0u, idx});
    return jax_normal(o.x ^ o.y);
  };

  const float NS = 0.15811388300841897f;
  const float xv0 = P.xpj[col];
  const float xv1 = P.xpj[H_N + col];

  u16* hxs[3]  = {P.hx0, P.hx1, P.hx2};
  u16* hxls[3] = {P.hx0l, P.hx1l, P.hx2l};
  int i0 = 0, i1 = 1, i2 = 2;
  float hp0 = 0.f;
  int stable = 0;
  float nzA = make_noise(P.ka[0]);
  float nzB = 0.f;

  // ---- init loop: cell1 -> publish/per-wave poll -> cell2 -> global agg
#pragma unroll 1
  for (int it = 0; it < 100; ++it) {
    f32x4 o0, o1;
    gemm_in(hxs[i0], hxls[i0], o0, o1);
    float av = reduce_sum(o0, o1);
    float pre = av + xv0 + NS * nzA;
    float hp1 = 0.8f * hp0 + 0.2f * fmaxf(pre, 0.f);
    { u16 hb = f2bf(hp1);
      st_agent_u16(hxs[i1] + xoff, hb);
      st_agent_u16(hxls[i1] + xoff, f2bf(hp1 - bf2f(hb))); }
    publish(P.initflag, (u32)(it + 1));
    nzB = make_noise(P.kb[it]);      // hides flag RTT
    pollW(ifw, (u32)(it + 1));       // my 8 producers wrote i1

    gemm_in(hxs[i1], hxls[i1], o0, o1);
    av = reduce_sum(o0, o1);
    pre = av + xv1 + NS * nzB;
    float hp2 = 0.8f * hp1 + 0.2f * fmaxf(pre, 0.f);
    { u16 hb = f2bf(hp2);
      st_agent_u16(hxs[i2] + xoff, hb);
      st_agent_u16(hxls[i2] + xoff, f2bf(hp2 - bf2f(hb))); }
    float lmax = fabsf(hp2 - hp0);
#pragma unroll
    for (int off = 32; off >= 1; off >>= 1)
      lmax = fmaxf(lmax, __shfl_down(lmax, off));
    if (lane == 0) red[wv] = lmax;
    nzA = make_noise(P.ka[it + 1]);  // hides store ack
    bar_agg();                       // global: orders i2 writes + convergence

    bool close = (((u32*)red)[8] & 1u) != 0u;
    if (close) {
      if (++stable >= 4) break;
    } else stable = 0;
    int tmp = i0; i0 = i2; i2 = tmp;   // h0 <- h2
    hp0 = hp2;
  }

  // ---- main scan: dataflow, 3 rotating buffers, per-wave 8-flag gates
  u16* bufs[3] = {P.hxS0, P.hxS1, P.hxS2};
  st_agent_u16(bufs[0] + xoff, f2bf(hp0));   // publish h0
  publish(P.scanflag, 1u);
  float nzS = make_noise(P.ks[0]);
  float xv = P.hidden[idx];
  float hp = hp0;
#pragma unroll 1
  for (int t = 0; t < T_N; ++t) {
    pollW(sfw, (u32)(t + 1));                // h_t available from my producers
    f32x4 o0, o1;
    gemm_sc(bufs[t % 3], o0, o1);
    float av = reduce_sum(o0, o1);
    float pre = av + xv + NS * nzS;
    float hn = 0.8f * hp + 0.2f * fmaxf(pre, 0.f);
    hp = hn;
    if (t != T_N - 1) {
      st_agent_u16(bufs[(t + 1) % 3] + xoff, f2bf(hn));
      publish(P.scanflag, (u32)(t + 2));
      P.hidden[(size_t)t * BH + idx] = hn;   // off the pre-release ack path
      nzS = make_noise(P.ks[t + 1]);         // hides flag RTT
      xv = P.hidden[(size_t)(t + 1) * BH + idx];
    } else {
      P.hidden[(size_t)t * BH + idx] = hn;
    }
  }
}

// ---- output GEMM: out[M=16384][256] = hidden(bf16) @ Wout^T (hi+lo)
__global__ void __launch_bounds__(256) out_gemm(const float* __restrict__ hidden,
    const u16* __restrict__ wo_hi, const u16* __restrict__ wo_lo, float* __restrict__ out) {
  int lane = threadIdx.x & 63, wv = threadIdx.x >> 6;
  int mb = blockIdx.x * 64 + wv * 16;
  int arow = mb + (lane & 15);
  int q = lane >> 4;
  f32x4 acc[16];
#pragma unroll
  for (int n = 0; n < 16; ++n) acc[n] = {0.f, 0.f, 0.f, 0.f};
  const float* ap = hidden + (size_t)arow * H_N + q * 8;
#pragma unroll 2
  for (int c = 0; c < 64; ++c) {
    const float4* a4 = reinterpret_cast<const float4*>(ap + c * 32);
    float4 f0 = a4[0], f1 = a4[1];
    us8 av;
    av[0] = f2bf(f0.x); av[1] = f2bf(f0.y); av[2] = f2bf(f0.z); av[3] = f2bf(f0.w);
    av[4] = f2bf(f1.x); av[5] = f2bf(f1.y); av[6] = f2bf(f1.z); av[7] = f2bf(f1.w);
    bf16x8 a = __builtin_bit_cast(bf16x8, av);
#pragma unroll
    for (int n = 0; n < 16; ++n) {
      bf16x8 bh = ld8(wo_hi + ((size_t)(n * 64 + c) * 64 + lane) * 8);
      bf16x8 bl = ld8(wo_lo + ((size_t)(n * 64 + c) * 64 + lane) * 8);
      acc[n] = mfma16(a, bh, acc[n]);
      acc[n] = mfma16(a, bl, acc[n]);
    }
  }
#pragma unroll
  for (int n = 0; n < 16; ++n)
#pragma unroll
    for (int r = 0; r < 4; ++r)
      out[(size_t)(mb + q * 4 + r) * NOUT_N + n * 16 + (lane & 15)] = acc[n][r];
}

extern "C" void kernel_launch(void* const* d_in, const int* in_sizes, int n_in,
                              void* d_out, int out_size, void* d_ws, size_t ws_size,
                              hipStream_t stream) {
  const float* x = (const float*)d_in[0];
  const float* W_ih = (const float*)d_in[1];
  const float* W_hh = (const float*)d_in[2];
  const float* bias = (const float*)d_in[3];
  const float* W_out = (const float*)d_in[4];
  float* out = (float*)d_out;

  char* ws = (char*)d_ws;
  size_t off = 0;
  auto alloc = [&](size_t bytes) -> void* {
    void* p = ws + off;
    off += (bytes + 255) & ~(size_t)255;
    return p;
  };
  u16* whh_hi = (u16*)alloc(8388608);
  u16* whh_lo = (u16*)alloc(8388608);
  u16* wih_hi = (u16*)alloc(1048576);
  u16* wih_lo = (u16*)alloc(1048576);
  u16* wout_hi = (u16*)alloc(1048576);
  u16* wout_lo = (u16*)alloc(1048576);
  u16* xp_hi = (u16*)alloc(8388608);
  u16* xp_lo = (u16*)alloc(8388608);
  float* xpj = (float*)alloc(16384);
  u16* hx0 = (u16*)alloc(262144);
  u16* hx1 = (u16*)alloc(262144);
  u16* hx2 = (u16*)alloc(262144);
  u16* hx0l = (u16*)alloc(262144);
  u16* hx1l = (u16*)alloc(262144);
  u16* hx2l = (u16*)alloc(262144);
  u16* hxS0 = (u16*)alloc(262144);
  u16* hxS1 = (u16*)alloc(262144);
  u16* hxS2 = (u16*)alloc(262144);
  U2* ka = (U2*)alloc(832);
  U2* kb = (U2*)alloc(832);
  U2* ks = (U2*)alloc(2048);
  u32* bar = (u32*)alloc(4096);

  float* hidden = out + OUT_SZ;

  hipLaunchKernelGGL(pack_b_kernel, dim3(2048), dim3(256), 0, stream, W_hh, whh_hi, whh_lo, 2048, 6);
  hipLaunchKernelGGL(pack_b_kernel, dim3(256), dim3(256), 0, stream, W_ih, wih_hi, wih_lo, 256, 3);
  hipLaunchKernelGGL(pack_b_kernel, dim3(256), dim3(256), 0, stream, W_out, wout_hi, wout_lo, 2048, 6);
  hipLaunchKernelGGL(pack_x_kernel, dim3(2048), dim3(256), 0, stream, x, xp_hi, xp_lo);
  hipLaunchKernelGGL(probe_proj, dim3(16), dim3(256), 0, stream, x, W_ih, bias, xpj);
  hipLaunchKernelGGL(setup_keys, dim3(1), dim3(256), 0, stream, ka, kb, ks);
  hipLaunchKernelGGL(zero_bufs, dim3(256), dim3(256), 0, stream, (u32*)hx0, (u32*)hx0l, bar);
  hipLaunchKernelGGL(xproj_gemm, dim3(32768), dim3(256), 0, stream, xp_hi, xp_lo, wih_hi, wih_lo, bias, hidden);

  RnnParams P;
  P.whh_hi = whh_hi; P.whh_lo = whh_lo;
  P.xpj = xpj;
  P.hidden = hidden;
  P.hx0 = hx0; P.hx1 = hx1; P.hx2 = hx2;
  P.hx0l = hx0l; P.hx1l = hx1l; P.hx2l = hx2l;
  P.hxS0 = hxS0; P.hxS1 = hxS1; P.hxS2 = hxS2;
  P.ka = ka; P.kb = kb; P.ks = ks;
  P.slots = bar; P.mslot = bar + 256;
  P.initflag = bar + 512; P.scanflag = bar + 768;

  static bool attr_set = false;
  if (!attr_set) {
    hipFuncSetAttribute((const void*)rnn_persistent,
                        hipFuncAttributeMaxDynamicSharedMemorySize, LDS_BYTES);
    attr_set = true;
  }

  void* kargs[] = {(void*)&P};
  hipLaunchCooperativeKernel((const void*)rnn_persistent, dim3(256), dim3(512), kargs, LDS_BYTES, stream);

  hipLaunchKernelGGL(out_gemm, dim3(256), dim3(256), 0, stream, hidden, wout_hi, wout_lo, out);
}